// Round 10
// baseline (291.440 us; speedup 1.0000x reference)
//
#include <hip/hip_runtime.h>
#include <math.h>

// GCN forward: 3x GCNConv (128->4->4->2) + classifier (2->4).
// CSR build with ZERO global atomics: chunk-hist (128-node dst buckets) ->
// parallel scans -> partition -> per-bucket LDS counting-sort (k_build, also
// emits dinv + rowoff). Aggregation = owner-computes gather (no atomics).
// r9 lesson: k_part write-amp is eviction-before-fill; CHUNK=50000 (G=128)
// makes runs 256B (2 lines) and caps open-line set at ~3.2MB/XCD.

#define CHUNK 50000
#define MAXNB 1024     // 128-node buckets; n <= 131071
#define CAP   12288    // max edges staged per bucket (avg 8184, sigma~90)

// XCD-contiguous chunk assignment (bijective when G%8==0, else identity).
__device__ __forceinline__ int swz_chunk(int bid, int G) {
    if ((G & 7) != 0) return bid;
    return (bid & 7) * (G >> 3) + (bid >> 3);
}

// Chunk histogram over 128-node dst buckets, transposed store hbT[b][g].
__global__ void k_hist(const int* __restrict__ dst, int* __restrict__ hbT,
                       int NB, int G, int e) {
    __shared__ int hist[MAXNB];
    int g = swz_chunk(blockIdx.x, G);
    for (int b = threadIdx.x; b < NB; b += 512) hist[b] = 0;
    __syncthreads();
    long long i0 = (long long)g * CHUNK;
    int i1 = (int)min(i0 + CHUNK, (long long)e);
    for (int i = (int)i0 + threadIdx.x; i < i1; i += 512)
        atomicAdd(&hist[dst[i] >> 7], 1);
    __syncthreads();
    for (int b = threadIdx.x; b < NB; b += 512)
        hbT[(size_t)b * G + g] = hist[b];
}

// Per-bucket exclusive scan over chunks (block per bucket, contiguous row).
__global__ void k_scanA(int* __restrict__ hbT, int* __restrict__ btot, int G) {
    __shared__ int part[256];
    int b = blockIdx.x, t = threadIdx.x;
    int* row = hbT + (size_t)b * G;
    int C = (G + 255) / 256;
    int lo = t * C, hi = min(lo + C, G);
    int s = 0;
    for (int i = lo; i < hi; i++) s += row[i];
    part[t] = s;
    __syncthreads();
#pragma unroll
    for (int off = 1; off < 256; off <<= 1) {
        int u = (t >= off) ? part[t - off] : 0;
        __syncthreads();
        part[t] += u;
        __syncthreads();
    }
    int run = part[t] - s;
    for (int i = lo; i < hi; i++) {
        int v = row[i];
        row[i] = run;
        run += v;
    }
    if (t == 255) btot[b] = part[255];
}

// Exclusive scan of NB bucket totals -> bstart.
__global__ void k_scanB(const int* __restrict__ btot, int* __restrict__ bstart,
                        int NB, int e) {
    __shared__ int part[512];
    int t = threadIdx.x;
    int C = (NB + 511) / 512;
    int lo = t * C, hi = min(lo + C, NB);
    int s = 0;
    for (int i = lo; i < hi; i++) s += btot[i];
    part[t] = s;
    __syncthreads();
#pragma unroll
    for (int off = 1; off < 512; off <<= 1) {
        int u = (t >= off) ? part[t - off] : 0;
        __syncthreads();
        part[t] += u;
        __syncthreads();
    }
    int run = part[t] - s;
    for (int i = lo; i < hi; i++) {
        bstart[i] = run;
        run += btot[i];
    }
    if (t == 511) bstart[NB] = e;
}

// Partition edges into 128-node dst buckets. packed = (dst&127)<<17 | src.
__global__ void k_part(const int* __restrict__ src, const int* __restrict__ dst,
                       const int* __restrict__ hbT, const int* __restrict__ bstart,
                       int* __restrict__ packed, int NB, int G, int e) {
    __shared__ int cur[MAXNB];
    int g = swz_chunk(blockIdx.x, G);
    for (int b = threadIdx.x; b < NB; b += 512)
        cur[b] = hbT[(size_t)b * G + g] + bstart[b];
    __syncthreads();
    long long i0 = (long long)g * CHUNK;
    int i1 = (int)min(i0 + CHUNK, (long long)e);
    for (int i = (int)i0 + threadIdx.x; i < i1; i += 512) {
        int d = dst[i], s = src[i];
        int pos = atomicAdd(&cur[d >> 7], 1);
        packed[pos] = ((d & 127) << 17) | s;
    }
}

// Per-bucket counting sort (in place): stage bucket in LDS, histogram 128
// dst-locals, scan, emit dinv + rowoff, permute srcs back to per-node runs.
__global__ void k_build(const int* __restrict__ bstart, int* __restrict__ packed,
                        float* __restrict__ dinv, int* __restrict__ rowoff, int n) {
    __shared__ int stage[CAP];
    __shared__ int cnt[128];
    __shared__ int off[128];
    __shared__ int cur[128];
    int b = blockIdx.x, tid = threadIdx.x;
    int lo = bstart[b];
    int len = bstart[b + 1] - lo;
    if (len > CAP) len = CAP;  // safety clamp (len ~ Poisson(8184); never hit)
    if (tid < 128) cnt[tid] = 0;
    for (int i = tid; i < len; i += 256) stage[i] = packed[lo + i];
    __syncthreads();
    for (int i = tid; i < len; i += 256) atomicAdd(&cnt[stage[i] >> 17], 1);
    __syncthreads();
    if (tid < 128) off[tid] = cnt[tid];
    __syncthreads();
#pragma unroll
    for (int s = 1; s < 128; s <<= 1) {
        int v = 0;
        if (tid < 128 && tid >= s) v = off[tid - s];
        __syncthreads();
        if (tid < 128 && tid >= s) off[tid] += v;
        __syncthreads();
    }
    if (tid < 128) {
        int excl = off[tid] - cnt[tid];   // exclusive prefix
        int node = (b << 7) + tid;
        if (node < n) dinv[node] = 1.0f / sqrtf((float)(cnt[tid] + 1));
        if (node <= n) rowoff[node] = lo + excl;
        cur[tid] = excl;
    }
    __syncthreads();
    for (int i = tid; i < len; i += 256) {
        int w = stage[i];
        int p = atomicAdd(&cur[w >> 17], 1);
        packed[lo + p] = w & 0x1FFFF;     // store bare src; dst implicit by run
    }
}

// Layer 1 GEMV: one wave per node. hs = (x @ W1) * dinv.
__global__ void k_mm1(const float* __restrict__ x, const float* __restrict__ W,
                      const float* __restrict__ dinv, float* __restrict__ hs, int n) {
    int gid = blockIdx.x * blockDim.x + threadIdx.x;
    int node = gid >> 6;
    int lane = threadIdx.x & 63;
    if (node >= n) return;
    const float2 xv = *reinterpret_cast<const float2*>(x + (size_t)node * 128 + lane * 2);
    const float4 w0 = *reinterpret_cast<const float4*>(W + (lane * 2) * 4);
    const float4 w1 = *reinterpret_cast<const float4*>(W + (lane * 2 + 1) * 4);
    float a0 = xv.x * w0.x + xv.y * w1.x;
    float a1 = xv.x * w0.y + xv.y * w1.y;
    float a2 = xv.x * w0.z + xv.y * w1.z;
    float a3 = xv.x * w0.w + xv.y * w1.w;
#pragma unroll
    for (int m = 32; m >= 1; m >>= 1) {
        a0 += __shfl_xor(a0, m);
        a1 += __shfl_xor(a1, m);
        a2 += __shfl_xor(a2, m);
        a3 += __shfl_xor(a3, m);
    }
    if (lane == 0) {
        float di = dinv[node];
        *reinterpret_cast<float4*>(hs + (size_t)node * 4) =
            make_float4(a0 * di, a1 * di, a2 * di, a3 * di);
    }
}

// Gather + finalize, 4-wide hs. One wave per node, coalesced row read,
// divergent hs gather, register butterfly reduce. No atomics.
template <int FOUT>
__global__ void k_gath_fin4(const int* __restrict__ rowoff, const int* __restrict__ csr,
                            const float* __restrict__ hs, const float* __restrict__ dinv,
                            const float* __restrict__ b, const float* __restrict__ Wn,
                            float* __restrict__ hsn, int n) {
    int gid = blockIdx.x * blockDim.x + threadIdx.x;
    int node = gid >> 6;
    int lane = threadIdx.x & 63;
    if (node >= n) return;
    int start = rowoff[node], end = rowoff[node + 1];
    float a0 = 0.f, a1 = 0.f, a2 = 0.f, a3 = 0.f;
    for (int j = start + lane; j < end; j += 64) {
        int s = csr[j];
        float4 v = *reinterpret_cast<const float4*>(hs + (size_t)s * 4);
        a0 += v.x; a1 += v.y; a2 += v.z; a3 += v.w;
    }
#pragma unroll
    for (int m = 32; m >= 1; m >>= 1) {
        a0 += __shfl_xor(a0, m);
        a1 += __shfl_xor(a1, m);
        a2 += __shfl_xor(a2, m);
        a3 += __shfl_xor(a3, m);
    }
    if (lane == 0) {
        float4 s = *reinterpret_cast<const float4*>(hs + (size_t)node * 4);
        float di = dinv[node];
        float h0 = tanhf((a0 + s.x) * di + b[0]);
        float h1 = tanhf((a1 + s.y) * di + b[1]);
        float h2 = tanhf((a2 + s.z) * di + b[2]);
        float h3 = tanhf((a3 + s.w) * di + b[3]);
        float o[FOUT];
#pragma unroll
        for (int j = 0; j < FOUT; j++) {
            o[j] = (h0 * Wn[0 * FOUT + j] + h1 * Wn[1 * FOUT + j] +
                    h2 * Wn[2 * FOUT + j] + h3 * Wn[3 * FOUT + j]) * di;
        }
        if constexpr (FOUT == 4) {
            *reinterpret_cast<float4*>(hsn + (size_t)node * 4) =
                make_float4(o[0], o[1], o[2], o[3]);
        } else {
            *reinterpret_cast<float2*>(hsn + (size_t)node * 2) = make_float2(o[0], o[1]);
        }
    }
}

// Final layer: gather float2, h3 = tanh(...) -> hout; out = h3@Wc + bc.
__global__ void k_gath_fin3(const int* __restrict__ rowoff, const int* __restrict__ csr,
                            const float* __restrict__ hs, const float* __restrict__ dinv,
                            const float* __restrict__ b3, const float* __restrict__ Wc,
                            const float* __restrict__ bc, float* __restrict__ out,
                            float* __restrict__ hout, int n) {
    int gid = blockIdx.x * blockDim.x + threadIdx.x;
    int node = gid >> 6;
    int lane = threadIdx.x & 63;
    if (node >= n) return;
    int start = rowoff[node], end = rowoff[node + 1];
    float a0 = 0.f, a1 = 0.f;
    for (int j = start + lane; j < end; j += 64) {
        int s = csr[j];
        float2 v = *reinterpret_cast<const float2*>(hs + (size_t)s * 2);
        a0 += v.x; a1 += v.y;
    }
#pragma unroll
    for (int m = 32; m >= 1; m >>= 1) {
        a0 += __shfl_xor(a0, m);
        a1 += __shfl_xor(a1, m);
    }
    if (lane == 0) {
        float2 s = *reinterpret_cast<const float2*>(hs + (size_t)node * 2);
        float di = dinv[node];
        float h0 = tanhf((a0 + s.x) * di + b3[0]);
        float h1 = tanhf((a1 + s.y) * di + b3[1]);
        *reinterpret_cast<float2*>(hout + (size_t)node * 2) = make_float2(h0, h1);
        float4 o;
        o.x = h0 * Wc[0] + h1 * Wc[4] + bc[0];
        o.y = h0 * Wc[1] + h1 * Wc[5] + bc[1];
        o.z = h0 * Wc[2] + h1 * Wc[6] + bc[2];
        o.w = h0 * Wc[3] + h1 * Wc[7] + bc[3];
        *reinterpret_cast<float4*>(out + (size_t)node * 4) = o;
    }
}

extern "C" void kernel_launch(void* const* d_in, const int* in_sizes, int n_in,
                              void* d_out, int out_size, void* d_ws, size_t ws_size,
                              hipStream_t stream) {
    const float* x  = (const float*)d_in[0];
    const int*  ei  = (const int*)d_in[1];
    const float* W1 = (const float*)d_in[2];
    const float* b1 = (const float*)d_in[3];
    const float* W2 = (const float*)d_in[4];
    const float* b2 = (const float*)d_in[5];
    const float* W3 = (const float*)d_in[6];
    const float* b3 = (const float*)d_in[7];
    const float* Wc = (const float*)d_in[8];
    const float* bc = (const float*)d_in[9];

    const int n = in_sizes[0] / 128;
    const int e = in_sizes[1] / 2;
    const int* src = ei;
    const int* dst = ei + e;

    const int NB = (n + 127) >> 7;            // 128-node dst buckets (782)
    const int G  = (e + CHUNK - 1) / CHUNK;   // edge chunks (128)

    const size_t MB = 1024 * 1024;
    char* ws = (char*)d_ws;
    float* dinv   = (float*)(ws + 0);                 // n floats
    float* hsA    = (float*)(ws + MB / 2);            // n*4 floats (1.6 MB)
    float* hsB    = (float*)(ws + 2 * MB + MB / 2);   // n*4 floats
    int*   rowoff = (int*)  (ws + 4 * MB + MB / 2);   // n+1 ints
    int*   btot   = (int*)  (ws + 5 * MB);            // NB ints
    int*   bstart = (int*)  (ws + 5 * MB + 16 * 1024);
    int*   hbT    = (int*)  (ws + 5 * MB + MB / 2);   // NB*G ints (~0.4 MB)
    int*   packed = (int*)  (ws + 8 * MB + MB / 2);   // e ints (25.6 MB)

    float* out  = (float*)d_out;
    float* hout = out + (size_t)n * 4;

    // CSR build, zero global atomics
    k_hist<<<G, 512, 0, stream>>>(dst, hbT, NB, G, e);
    k_scanA<<<NB, 256, 0, stream>>>(hbT, btot, G);
    k_scanB<<<1, 512, 0, stream>>>(btot, bstart, NB, e);
    k_part<<<G, 512, 0, stream>>>(src, dst, hbT, bstart, packed, NB, G, e);
    k_build<<<NB, 256, 0, stream>>>(bstart, packed, dinv, rowoff, n);

    // Layer 1 GEMV: hsA = (x @ W1) * dinv
    const int wb = (n + 3) / 4;
    k_mm1<<<wb, 256, 0, stream>>>(x, W1, dinv, hsA, n);

    // Layers 1..3: owner-computes gather + fused finalize
    k_gath_fin4<4><<<wb, 256, 0, stream>>>(rowoff, packed, hsA, dinv, b1, W2, hsB, n);
    k_gath_fin4<2><<<wb, 256, 0, stream>>>(rowoff, packed, hsB, dinv, b2, W3, hsA, n);
    k_gath_fin3<<<wb, 256, 0, stream>>>(rowoff, packed, hsA, dinv, b3, Wc, bc, out, hout, n);

    (void)n_in; (void)out_size; (void)ws_size;
}

// Round 11
// 262.191 us; speedup vs baseline: 1.1116x; 1.1116x over previous
//
#include <hip/hip_runtime.h>
#include <math.h>

// GCN forward: 3x GCNConv (128->4->4->2) + classifier (2->4).
// r10 lesson: scattered global STORES are the wall (dur insensitive to
// write-amp; 64 lanes -> 64 L2 transactions/inst). New build pipeline has
// ZERO scattered global writes and ZERO global atomics:
//   k_local: per-8192-edge chunk LDS counting sort by 128-node bucket ->
//            coalesced sorted-chunk writeback + counts(hbT) + offsets(loff)
//   scanA/scanB: per-bucket cross-chunk scan -> bstart
//   k_merge: per-bucket gather of chunk runs (scattered READS - benign),
//            LDS counting sort by node -> coalesced CSR + rowoff + dinv
// Aggregation: owner-computes gather, wave per node, register reduce.
// Fallback to the r9 path (global-scatter part) if ws_size < ~63MB.

#define LCHUNK 8192
#define CHUNK2 16000   // fallback path chunk
#define MAXNB  1024    // 128-node buckets; n <= 131071
#define CAP    12288   // max edges per bucket (avg 8184, sigma~90)

__device__ __forceinline__ int swz_chunk(int bid, int G) {
    if ((G & 7) != 0) return bid;
    return (bid & 7) * (G >> 3) + (bid >> 3);
}

// ---------- new path: chunk-local counting sort ----------
__global__ __launch_bounds__(512) void k_local(
        const int* __restrict__ src, const int* __restrict__ dst,
        int* __restrict__ packed, int* __restrict__ hbT, int* __restrict__ loff,
        int NBK, int G, int e) {
    __shared__ int hist[MAXNB];
    __shared__ int cur[MAXNB];
    __shared__ int part[512];
    __shared__ int stage[LCHUNK];
    int g = blockIdx.x, tid = threadIdx.x;
    for (int b = tid; b < NBK; b += 512) hist[b] = 0;
    __syncthreads();
    int i0 = g * LCHUNK;
    int i1 = min(i0 + LCHUNK, e);
    int val[16], bkt[16];
#pragma unroll
    for (int k = 0; k < 16; k++) {
        int i = i0 + tid + (k << 9);
        bool v = i < i1;
        int d = v ? dst[i] : 0;
        int s = v ? src[i] : 0;
        bkt[k] = v ? (d >> 7) : -1;
        val[k] = ((d & 127) << 17) | s;
        if (v) atomicAdd(&hist[d >> 7], 1);
    }
    __syncthreads();
    // block exclusive scan over NBK counts (2 buckets per thread)
    int lo = tid * 2;
    int s0 = (lo < NBK) ? hist[lo] : 0;
    int s1 = (lo + 1 < NBK) ? hist[lo + 1] : 0;
    int sum = s0 + s1;
    part[tid] = sum;
    __syncthreads();
#pragma unroll
    for (int off = 1; off < 512; off <<= 1) {
        int u = (tid >= off) ? part[tid - off] : 0;
        __syncthreads();
        part[tid] += u;
        __syncthreads();
    }
    int excl = part[tid] - sum;
    if (lo < NBK) {
        cur[lo] = excl;
        hbT[(size_t)lo * G + g] = s0;
        loff[(size_t)g * NBK + lo] = excl;
    }
    if (lo + 1 < NBK) {
        cur[lo + 1] = excl + s0;
        hbT[(size_t)(lo + 1) * G + g] = s1;
        loff[(size_t)g * NBK + lo + 1] = excl + s0;
    }
    __syncthreads();
#pragma unroll
    for (int k = 0; k < 16; k++) {
        if (bkt[k] >= 0) {
            int p = atomicAdd(&cur[bkt[k]], 1);
            stage[p] = val[k];
        }
    }
    __syncthreads();
    int len = i1 - i0;
    for (int i = tid; i < len; i += 512)
        packed[i0 + i] = stage[i];
}

// Per-bucket exclusive scan over chunks (block per bucket, contiguous row).
__global__ void k_scanA(int* __restrict__ hbT, int* __restrict__ btot, int G) {
    __shared__ int part[256];
    int b = blockIdx.x, t = threadIdx.x;
    int* row = hbT + (size_t)b * G;
    int C = (G + 255) / 256;
    int lo = t * C, hi = min(lo + C, G);
    int s = 0;
    for (int i = lo; i < hi; i++) s += row[i];
    part[t] = s;
    __syncthreads();
#pragma unroll
    for (int off = 1; off < 256; off <<= 1) {
        int u = (t >= off) ? part[t - off] : 0;
        __syncthreads();
        part[t] += u;
        __syncthreads();
    }
    int run = part[t] - s;
    for (int i = lo; i < hi; i++) {
        int v = row[i];
        row[i] = run;
        run += v;
    }
    if (t == 255) btot[b] = part[255];
}

__global__ void k_scanB(const int* __restrict__ btot, int* __restrict__ bstart,
                        int NB, int e) {
    __shared__ int part[512];
    int t = threadIdx.x;
    int C = (NB + 511) / 512;
    int lo = t * C, hi = min(lo + C, NB);
    int s = 0;
    for (int i = lo; i < hi; i++) s += btot[i];
    part[t] = s;
    __syncthreads();
#pragma unroll
    for (int off = 1; off < 512; off <<= 1) {
        int u = (t >= off) ? part[t - off] : 0;
        __syncthreads();
        part[t] += u;
        __syncthreads();
    }
    int run = part[t] - s;
    for (int i = lo; i < hi; i++) {
        bstart[i] = run;
        run += btot[i];
    }
    if (t == 511) bstart[NB] = e;
}

// Merge runs of one bucket, counting-sort by node, emit CSR+rowoff+dinv.
__global__ void k_merge(const int* __restrict__ hbT, const int* __restrict__ loff,
                        const int* __restrict__ btot, const int* __restrict__ bstart,
                        const int* __restrict__ packed, int* __restrict__ csr,
                        float* __restrict__ dinv, int* __restrict__ rowoff,
                        int NBK, int G, int n) {
    __shared__ int stage[CAP];
    __shared__ int cnt[128];
    __shared__ int off[128];
    __shared__ int cur[128];
    int b = blockIdx.x, tid = threadIdx.x;
    int total = btot[b];
    if (total > CAP) total = CAP;
    for (int g = tid; g < G; g += 256) {
        int o  = hbT[(size_t)b * G + g];
        int nx = (g + 1 < G) ? hbT[(size_t)b * G + g + 1] : btot[b];
        if (nx > CAP) nx = CAP;
        if (o >= nx) continue;
        int sp = g * LCHUNK + loff[(size_t)g * NBK + b];
        for (int k = o; k < nx; k++) stage[k] = packed[sp + (k - o)];
    }
    if (tid < 128) cnt[tid] = 0;
    __syncthreads();
    for (int i = tid; i < total; i += 256) atomicAdd(&cnt[stage[i] >> 17], 1);
    __syncthreads();
    if (tid < 128) off[tid] = cnt[tid];
    __syncthreads();
#pragma unroll
    for (int s = 1; s < 128; s <<= 1) {
        int v = 0;
        if (tid < 128 && tid >= s) v = off[tid - s];
        __syncthreads();
        if (tid < 128 && tid >= s) off[tid] += v;
        __syncthreads();
    }
    if (tid < 128) {
        int excl = off[tid] - cnt[tid];
        int node = (b << 7) + tid;
        if (node < n) dinv[node] = 1.0f / sqrtf((float)(cnt[tid] + 1));
        if (node <= n) rowoff[node] = bstart[b] + excl;
        cur[tid] = excl;
    }
    __syncthreads();
    int base = bstart[b];
    for (int i = tid; i < total; i += 256) {
        int w = stage[i];
        int p = atomicAdd(&cur[w >> 17], 1);
        csr[base + p] = w & 0x1FFFF;
    }
}

// ---------- fallback path (r9): global-scatter partition ----------
__global__ void k_hist_o(const int* __restrict__ dst, int* __restrict__ hbT,
                         int NB, int G, int e) {
    __shared__ int hist[MAXNB];
    int g = swz_chunk(blockIdx.x, G);
    for (int b = threadIdx.x; b < NB; b += 512) hist[b] = 0;
    __syncthreads();
    long long i0 = (long long)g * CHUNK2;
    int i1 = (int)min(i0 + CHUNK2, (long long)e);
    for (int i = (int)i0 + threadIdx.x; i < i1; i += 512)
        atomicAdd(&hist[dst[i] >> 7], 1);
    __syncthreads();
    for (int b = threadIdx.x; b < NB; b += 512)
        hbT[(size_t)b * G + g] = hist[b];
}

__global__ void k_part_o(const int* __restrict__ src, const int* __restrict__ dst,
                         const int* __restrict__ hbT, const int* __restrict__ bstart,
                         int* __restrict__ packed, int NB, int G, int e) {
    __shared__ int cur[MAXNB];
    int g = swz_chunk(blockIdx.x, G);
    for (int b = threadIdx.x; b < NB; b += 512)
        cur[b] = hbT[(size_t)b * G + g] + bstart[b];
    __syncthreads();
    long long i0 = (long long)g * CHUNK2;
    int i1 = (int)min(i0 + CHUNK2, (long long)e);
    for (int i = (int)i0 + threadIdx.x; i < i1; i += 512) {
        int d = dst[i], s = src[i];
        int pos = atomicAdd(&cur[d >> 7], 1);
        packed[pos] = ((d & 127) << 17) | s;
    }
}

__global__ void k_build_o(const int* __restrict__ bstart, int* __restrict__ packed,
                          float* __restrict__ dinv, int* __restrict__ rowoff, int n) {
    __shared__ int stage[CAP];
    __shared__ int cnt[128];
    __shared__ int off[128];
    __shared__ int cur[128];
    int b = blockIdx.x, tid = threadIdx.x;
    int lo = bstart[b];
    int len = bstart[b + 1] - lo;
    if (len > CAP) len = CAP;
    if (tid < 128) cnt[tid] = 0;
    for (int i = tid; i < len; i += 256) stage[i] = packed[lo + i];
    __syncthreads();
    for (int i = tid; i < len; i += 256) atomicAdd(&cnt[stage[i] >> 17], 1);
    __syncthreads();
    if (tid < 128) off[tid] = cnt[tid];
    __syncthreads();
#pragma unroll
    for (int s = 1; s < 128; s <<= 1) {
        int v = 0;
        if (tid < 128 && tid >= s) v = off[tid - s];
        __syncthreads();
        if (tid < 128 && tid >= s) off[tid] += v;
        __syncthreads();
    }
    if (tid < 128) {
        int excl = off[tid] - cnt[tid];
        int node = (b << 7) + tid;
        if (node < n) dinv[node] = 1.0f / sqrtf((float)(cnt[tid] + 1));
        if (node <= n) rowoff[node] = lo + excl;
        cur[tid] = excl;
    }
    __syncthreads();
    for (int i = tid; i < len; i += 256) {
        int w = stage[i];
        int p = atomicAdd(&cur[w >> 17], 1);
        packed[lo + p] = w & 0x1FFFF;
    }
}

// ---------- compute kernels ----------
__global__ void k_mm1(const float* __restrict__ x, const float* __restrict__ W,
                      const float* __restrict__ dinv, float* __restrict__ hs, int n) {
    int gid = blockIdx.x * blockDim.x + threadIdx.x;
    int node = gid >> 6;
    int lane = threadIdx.x & 63;
    if (node >= n) return;
    const float2 xv = *reinterpret_cast<const float2*>(x + (size_t)node * 128 + lane * 2);
    const float4 w0 = *reinterpret_cast<const float4*>(W + (lane * 2) * 4);
    const float4 w1 = *reinterpret_cast<const float4*>(W + (lane * 2 + 1) * 4);
    float a0 = xv.x * w0.x + xv.y * w1.x;
    float a1 = xv.x * w0.y + xv.y * w1.y;
    float a2 = xv.x * w0.z + xv.y * w1.z;
    float a3 = xv.x * w0.w + xv.y * w1.w;
#pragma unroll
    for (int m = 32; m >= 1; m >>= 1) {
        a0 += __shfl_xor(a0, m);
        a1 += __shfl_xor(a1, m);
        a2 += __shfl_xor(a2, m);
        a3 += __shfl_xor(a3, m);
    }
    if (lane == 0) {
        float di = dinv[node];
        *reinterpret_cast<float4*>(hs + (size_t)node * 4) =
            make_float4(a0 * di, a1 * di, a2 * di, a3 * di);
    }
}

template <int FOUT>
__global__ void k_gath_fin4(const int* __restrict__ rowoff, const int* __restrict__ csr,
                            const float* __restrict__ hs, const float* __restrict__ dinv,
                            const float* __restrict__ b, const float* __restrict__ Wn,
                            float* __restrict__ hsn, int n) {
    int gid = blockIdx.x * blockDim.x + threadIdx.x;
    int node = gid >> 6;
    int lane = threadIdx.x & 63;
    if (node >= n) return;
    int start = rowoff[node], end = rowoff[node + 1];
    float a0 = 0.f, a1 = 0.f, a2 = 0.f, a3 = 0.f;
    for (int j = start + lane; j < end; j += 64) {
        int s = csr[j];
        float4 v = *reinterpret_cast<const float4*>(hs + (size_t)s * 4);
        a0 += v.x; a1 += v.y; a2 += v.z; a3 += v.w;
    }
#pragma unroll
    for (int m = 32; m >= 1; m >>= 1) {
        a0 += __shfl_xor(a0, m);
        a1 += __shfl_xor(a1, m);
        a2 += __shfl_xor(a2, m);
        a3 += __shfl_xor(a3, m);
    }
    if (lane == 0) {
        float4 s = *reinterpret_cast<const float4*>(hs + (size_t)node * 4);
        float di = dinv[node];
        float h0 = tanhf((a0 + s.x) * di + b[0]);
        float h1 = tanhf((a1 + s.y) * di + b[1]);
        float h2 = tanhf((a2 + s.z) * di + b[2]);
        float h3 = tanhf((a3 + s.w) * di + b[3]);
        float o[FOUT];
#pragma unroll
        for (int j = 0; j < FOUT; j++) {
            o[j] = (h0 * Wn[0 * FOUT + j] + h1 * Wn[1 * FOUT + j] +
                    h2 * Wn[2 * FOUT + j] + h3 * Wn[3 * FOUT + j]) * di;
        }
        if constexpr (FOUT == 4) {
            *reinterpret_cast<float4*>(hsn + (size_t)node * 4) =
                make_float4(o[0], o[1], o[2], o[3]);
        } else {
            *reinterpret_cast<float2*>(hsn + (size_t)node * 2) = make_float2(o[0], o[1]);
        }
    }
}

__global__ void k_gath_fin3(const int* __restrict__ rowoff, const int* __restrict__ csr,
                            const float* __restrict__ hs, const float* __restrict__ dinv,
                            const float* __restrict__ b3, const float* __restrict__ Wc,
                            const float* __restrict__ bc, float* __restrict__ out,
                            float* __restrict__ hout, int n) {
    int gid = blockIdx.x * blockDim.x + threadIdx.x;
    int node = gid >> 6;
    int lane = threadIdx.x & 63;
    if (node >= n) return;
    int start = rowoff[node], end = rowoff[node + 1];
    float a0 = 0.f, a1 = 0.f;
    for (int j = start + lane; j < end; j += 64) {
        int s = csr[j];
        float2 v = *reinterpret_cast<const float2*>(hs + (size_t)s * 2);
        a0 += v.x; a1 += v.y;
    }
#pragma unroll
    for (int m = 32; m >= 1; m >>= 1) {
        a0 += __shfl_xor(a0, m);
        a1 += __shfl_xor(a1, m);
    }
    if (lane == 0) {
        float2 s = *reinterpret_cast<const float2*>(hs + (size_t)node * 2);
        float di = dinv[node];
        float h0 = tanhf((a0 + s.x) * di + b3[0]);
        float h1 = tanhf((a1 + s.y) * di + b3[1]);
        *reinterpret_cast<float2*>(hout + (size_t)node * 2) = make_float2(h0, h1);
        float4 o;
        o.x = h0 * Wc[0] + h1 * Wc[4] + bc[0];
        o.y = h0 * Wc[1] + h1 * Wc[5] + bc[1];
        o.z = h0 * Wc[2] + h1 * Wc[6] + bc[2];
        o.w = h0 * Wc[3] + h1 * Wc[7] + bc[3];
        *reinterpret_cast<float4*>(out + (size_t)node * 4) = o;
    }
}

extern "C" void kernel_launch(void* const* d_in, const int* in_sizes, int n_in,
                              void* d_out, int out_size, void* d_ws, size_t ws_size,
                              hipStream_t stream) {
    const float* x  = (const float*)d_in[0];
    const int*  ei  = (const int*)d_in[1];
    const float* W1 = (const float*)d_in[2];
    const float* b1 = (const float*)d_in[3];
    const float* W2 = (const float*)d_in[4];
    const float* b2 = (const float*)d_in[5];
    const float* W3 = (const float*)d_in[6];
    const float* b3 = (const float*)d_in[7];
    const float* Wc = (const float*)d_in[8];
    const float* bc = (const float*)d_in[9];

    const int n = in_sizes[0] / 128;
    const int e = in_sizes[1] / 2;
    const int* src = ei;
    const int* dst = ei + e;

    const int NBK = (n + 127) >> 7;              // 128-node buckets (782)

    const size_t MB = 1024 * 1024;
    char* ws = (char*)d_ws;
    float* dinv   = (float*)(ws + 0);                    // n floats
    float* hsA    = (float*)(ws + MB / 2);               // n*4 floats
    float* hsB    = (float*)(ws + 2 * MB + MB / 2);      // n*4 floats
    int*   rowoff = (int*)  (ws + 4 * MB + MB / 2);      // n+1 ints
    int*   btot   = (int*)  (ws + 5 * MB);               // NBK ints
    int*   bstart = (int*)  (ws + 5 * MB + 16 * 1024);   // NBK+1 ints
    int*   hbT    = (int*)  (ws + 5 * MB + MB / 2);      // NBK*G ints
    int*   loff   = (int*)  (ws + 8 * MB);               // G*NBK ints (new path)
    int*   packed = (int*)  (ws + 10 * MB + MB / 2);     // e ints (25.6 MB)
    int*   csr    = (int*)  (ws + 36 * MB + MB / 2);     // e ints (new path)

    float* out  = (float*)d_out;
    float* hout = out + (size_t)n * 4;

    const size_t need_new = 36 * MB + MB / 2 + (size_t)e * 4 + MB;
    const bool use_new = ws_size >= need_new;

    const int* csr_p;
    if (use_new) {
        const int G = (e + LCHUNK - 1) / LCHUNK;         // 782
        k_local<<<G, 512, 0, stream>>>(src, dst, packed, hbT, loff, NBK, G, e);
        k_scanA<<<NBK, 256, 0, stream>>>(hbT, btot, G);
        k_scanB<<<1, 512, 0, stream>>>(btot, bstart, NBK, e);
        k_merge<<<NBK, 256, 0, stream>>>(hbT, loff, btot, bstart, packed, csr,
                                         dinv, rowoff, NBK, G, n);
        csr_p = csr;
    } else {
        const int G2 = (e + CHUNK2 - 1) / CHUNK2;        // 400
        k_hist_o<<<G2, 512, 0, stream>>>(dst, hbT, NBK, G2, e);
        k_scanA<<<NBK, 256, 0, stream>>>(hbT, btot, G2);
        k_scanB<<<1, 512, 0, stream>>>(btot, bstart, NBK, e);
        k_part_o<<<G2, 512, 0, stream>>>(src, dst, hbT, bstart, packed, NBK, G2, e);
        k_build_o<<<NBK, 256, 0, stream>>>(bstart, packed, dinv, rowoff, n);
        csr_p = packed;
    }

    // Layer 1 GEMV: hsA = (x @ W1) * dinv
    const int wb = (n + 3) / 4;
    k_mm1<<<wb, 256, 0, stream>>>(x, W1, dinv, hsA, n);

    // Layers 1..3: owner-computes gather + fused finalize
    k_gath_fin4<4><<<wb, 256, 0, stream>>>(rowoff, csr_p, hsA, dinv, b1, W2, hsB, n);
    k_gath_fin4<2><<<wb, 256, 0, stream>>>(rowoff, csr_p, hsB, dinv, b2, W3, hsA, n);
    k_gath_fin3<<<wb, 256, 0, stream>>>(rowoff, csr_p, hsA, dinv, b3, Wc, bc, out, hout, n);

    (void)n_in; (void)out_size;
}

// Round 12
// 238.736 us; speedup vs baseline: 1.2208x; 1.0982x over previous
//
#include <hip/hip_runtime.h>
#include <math.h>

// GCN forward: 3x GCNConv (128->4->4->2) + classifier (2->4).
// Build pipeline: ZERO scattered global writes, ZERO global atomics:
//   k_local: per-16384-edge chunk LDS counting sort by 128-node bucket ->
//            coalesced sorted-chunk writeback + counts(hbT) + offsets(loff)
//   scanA/scanB: per-bucket cross-chunk scan -> bstart
//   k_merge: per-bucket gather of chunk runs (aligned int4 scattered READS),
//            LDS counting sort by node -> coalesced CSR + rowoff + dinv
// Aggregation: owner-computes gather, wave per node, register reduce.
// r11 lesson: merge was 6.4M scalar divergent loads @6.4cyc; now int4 runs
// of ~21 edges. Fallback to r9 path (global-scatter part) if ws too small.

#define LCHUNK 16384
#define CHUNK2 16000   // fallback path chunk
#define MAXNB  1024    // 128-node buckets; n <= 131071
#define CAP    9600    // max edges per bucket (mean 8192, sigma~90 -> +15sig)

__device__ __forceinline__ int swz_chunk(int bid, int G) {
    if ((G & 7) != 0) return bid;
    return (bid & 7) * (G >> 3) + (bid >> 3);
}

// ---------- chunk-local counting sort (16384 edges, 32/thread in regs) ----
__global__ __launch_bounds__(512) void k_local(
        const int* __restrict__ src, const int* __restrict__ dst,
        int* __restrict__ packed, int* __restrict__ hbT, int* __restrict__ loff,
        int NBK, int G, int e) {
    __shared__ int hist[MAXNB];
    __shared__ int cur[MAXNB];
    __shared__ int part[512];
    __shared__ int stage[LCHUNK];
    int g = blockIdx.x, tid = threadIdx.x;
    for (int b = tid; b < NBK; b += 512) hist[b] = 0;
    __syncthreads();
    int i0 = g * LCHUNK;
    int i1 = min(i0 + LCHUNK, e);
    int val[32], bkt[32];
#pragma unroll
    for (int k = 0; k < 32; k++) {
        int i = i0 + tid + (k << 9);
        bool v = i < i1;
        int d = v ? dst[i] : 0;
        int s = v ? src[i] : 0;
        bkt[k] = v ? (d >> 7) : -1;
        val[k] = ((d & 127) << 17) | s;
        if (v) atomicAdd(&hist[d >> 7], 1);
    }
    __syncthreads();
    // block exclusive scan over NBK counts (2 buckets per thread)
    int lo = tid * 2;
    int s0 = (lo < NBK) ? hist[lo] : 0;
    int s1 = (lo + 1 < NBK) ? hist[lo + 1] : 0;
    int sum = s0 + s1;
    part[tid] = sum;
    __syncthreads();
#pragma unroll
    for (int off = 1; off < 512; off <<= 1) {
        int u = (tid >= off) ? part[tid - off] : 0;
        __syncthreads();
        part[tid] += u;
        __syncthreads();
    }
    int excl = part[tid] - sum;
    if (lo < NBK) {
        cur[lo] = excl;
        hbT[(size_t)lo * G + g] = s0;
        loff[(size_t)g * NBK + lo] = excl;
    }
    if (lo + 1 < NBK) {
        cur[lo + 1] = excl + s0;
        hbT[(size_t)(lo + 1) * G + g] = s1;
        loff[(size_t)g * NBK + lo + 1] = excl + s0;
    }
    __syncthreads();
#pragma unroll
    for (int k = 0; k < 32; k++) {
        if (bkt[k] >= 0) {
            int p = atomicAdd(&cur[bkt[k]], 1);
            stage[p] = val[k];
        }
    }
    __syncthreads();
    int len = i1 - i0;
    for (int i = tid; i < len; i += 512)
        packed[i0 + i] = stage[i];
}

// Per-bucket exclusive scan over chunks (block per bucket, contiguous row).
__global__ void k_scanA(int* __restrict__ hbT, int* __restrict__ btot, int G) {
    __shared__ int part[256];
    int b = blockIdx.x, t = threadIdx.x;
    int* row = hbT + (size_t)b * G;
    int C = (G + 255) / 256;
    int lo = t * C, hi = min(lo + C, G);
    int s = 0;
    for (int i = lo; i < hi; i++) s += row[i];
    part[t] = s;
    __syncthreads();
#pragma unroll
    for (int off = 1; off < 256; off <<= 1) {
        int u = (t >= off) ? part[t - off] : 0;
        __syncthreads();
        part[t] += u;
        __syncthreads();
    }
    int run = part[t] - s;
    for (int i = lo; i < hi; i++) {
        int v = row[i];
        row[i] = run;
        run += v;
    }
    if (t == 255) btot[b] = part[255];
}

__global__ void k_scanB(const int* __restrict__ btot, int* __restrict__ bstart,
                        int NB, int e) {
    __shared__ int part[512];
    int t = threadIdx.x;
    int C = (NB + 511) / 512;
    int lo = t * C, hi = min(lo + C, NB);
    int s = 0;
    for (int i = lo; i < hi; i++) s += btot[i];
    part[t] = s;
    __syncthreads();
#pragma unroll
    for (int off = 1; off < 512; off <<= 1) {
        int u = (t >= off) ? part[t - off] : 0;
        __syncthreads();
        part[t] += u;
        __syncthreads();
    }
    int run = part[t] - s;
    for (int i = lo; i < hi; i++) {
        bstart[i] = run;
        run += btot[i];
    }
    if (t == 511) bstart[NB] = e;
}

// Merge runs of one bucket (aligned int4 reads), counting-sort by node,
// emit CSR + rowoff + dinv.
__global__ void k_merge(const int* __restrict__ hbT, const int* __restrict__ loff,
                        const int* __restrict__ btot, const int* __restrict__ bstart,
                        const int* __restrict__ packed, int* __restrict__ csr,
                        float* __restrict__ dinv, int* __restrict__ rowoff,
                        int NBK, int G, int n) {
    __shared__ int stage[CAP];
    __shared__ int cnt[128];
    __shared__ int off[128];
    __shared__ int cur[128];
    int b = blockIdx.x, tid = threadIdx.x;
    int btt = btot[b];
    int total = min(btt, CAP);
    for (int g = tid; g < G; g += 256) {
        int o  = hbT[(size_t)b * G + g];
        int nx = (g + 1 < G) ? hbT[(size_t)b * G + g + 1] : btt;
        if (nx > CAP) nx = CAP;
        if (o >= nx) continue;
        int len = nx - o;
        int sp = g * LCHUNK + loff[(size_t)g * NBK + b];
        int a   = sp & ~3;
        int rel = sp - a;                  // 0..3
        int n4  = (rel + len + 3) >> 2;
        for (int q = 0; q < n4; q++) {
            int4 w = *reinterpret_cast<const int4*>(packed + a + q * 4);
            int base = q * 4 - rel;        // index of w.x within run
            if (base >= 0 && base < len)     stage[o + base]     = w.x;
            if (base + 1 >= 0 && base + 1 < len) stage[o + base + 1] = w.y;
            if (base + 2 >= 0 && base + 2 < len) stage[o + base + 2] = w.z;
            if (base + 3 >= 0 && base + 3 < len) stage[o + base + 3] = w.w;
        }
    }
    if (tid < 128) cnt[tid] = 0;
    __syncthreads();
    for (int i = tid; i < total; i += 256) atomicAdd(&cnt[stage[i] >> 17], 1);
    __syncthreads();
    if (tid < 128) off[tid] = cnt[tid];
    __syncthreads();
#pragma unroll
    for (int s = 1; s < 128; s <<= 1) {
        int v = 0;
        if (tid < 128 && tid >= s) v = off[tid - s];
        __syncthreads();
        if (tid < 128 && tid >= s) off[tid] += v;
        __syncthreads();
    }
    if (tid < 128) {
        int excl = off[tid] - cnt[tid];
        int node = (b << 7) + tid;
        if (node < n) dinv[node] = 1.0f / sqrtf((float)(cnt[tid] + 1));
        if (node <= n) rowoff[node] = bstart[b] + excl;
        cur[tid] = excl;
    }
    __syncthreads();
    int base = bstart[b];
    for (int i = tid; i < total; i += 256) {
        int w = stage[i];
        int p = atomicAdd(&cur[w >> 17], 1);
        csr[base + p] = w & 0x1FFFF;
    }
}

// ---------- fallback path (r9): global-scatter partition ----------
__global__ void k_hist_o(const int* __restrict__ dst, int* __restrict__ hbT,
                         int NB, int G, int e) {
    __shared__ int hist[MAXNB];
    int g = swz_chunk(blockIdx.x, G);
    for (int b = threadIdx.x; b < NB; b += 512) hist[b] = 0;
    __syncthreads();
    long long i0 = (long long)g * CHUNK2;
    int i1 = (int)min(i0 + CHUNK2, (long long)e);
    for (int i = (int)i0 + threadIdx.x; i < i1; i += 512)
        atomicAdd(&hist[dst[i] >> 7], 1);
    __syncthreads();
    for (int b = threadIdx.x; b < NB; b += 512)
        hbT[(size_t)b * G + g] = hist[b];
}

__global__ void k_part_o(const int* __restrict__ src, const int* __restrict__ dst,
                         const int* __restrict__ hbT, const int* __restrict__ bstart,
                         int* __restrict__ packed, int NB, int G, int e) {
    __shared__ int cur[MAXNB];
    int g = swz_chunk(blockIdx.x, G);
    for (int b = threadIdx.x; b < NB; b += 512)
        cur[b] = hbT[(size_t)b * G + g] + bstart[b];
    __syncthreads();
    long long i0 = (long long)g * CHUNK2;
    int i1 = (int)min(i0 + CHUNK2, (long long)e);
    for (int i = (int)i0 + threadIdx.x; i < i1; i += 512) {
        int d = dst[i], s = src[i];
        int pos = atomicAdd(&cur[d >> 7], 1);
        packed[pos] = ((d & 127) << 17) | s;
    }
}

__global__ void k_build_o(const int* __restrict__ bstart, int* __restrict__ packed,
                          float* __restrict__ dinv, int* __restrict__ rowoff, int n) {
    __shared__ int stage[CAP];
    __shared__ int cnt[128];
    __shared__ int off[128];
    __shared__ int cur[128];
    int b = blockIdx.x, tid = threadIdx.x;
    int lo = bstart[b];
    int len = bstart[b + 1] - lo;
    if (len > CAP) len = CAP;
    if (tid < 128) cnt[tid] = 0;
    for (int i = tid; i < len; i += 256) stage[i] = packed[lo + i];
    __syncthreads();
    for (int i = tid; i < len; i += 256) atomicAdd(&cnt[stage[i] >> 17], 1);
    __syncthreads();
    if (tid < 128) off[tid] = cnt[tid];
    __syncthreads();
#pragma unroll
    for (int s = 1; s < 128; s <<= 1) {
        int v = 0;
        if (tid < 128 && tid >= s) v = off[tid - s];
        __syncthreads();
        if (tid < 128 && tid >= s) off[tid] += v;
        __syncthreads();
    }
    if (tid < 128) {
        int excl = off[tid] - cnt[tid];
        int node = (b << 7) + tid;
        if (node < n) dinv[node] = 1.0f / sqrtf((float)(cnt[tid] + 1));
        if (node <= n) rowoff[node] = lo + excl;
        cur[tid] = excl;
    }
    __syncthreads();
    for (int i = tid; i < len; i += 256) {
        int w = stage[i];
        int p = atomicAdd(&cur[w >> 17], 1);
        packed[lo + p] = w & 0x1FFFF;
    }
}

// ---------- compute kernels ----------
__global__ void k_mm1(const float* __restrict__ x, const float* __restrict__ W,
                      const float* __restrict__ dinv, float* __restrict__ hs, int n) {
    int gid = blockIdx.x * blockDim.x + threadIdx.x;
    int node = gid >> 6;
    int lane = threadIdx.x & 63;
    if (node >= n) return;
    const float2 xv = *reinterpret_cast<const float2*>(x + (size_t)node * 128 + lane * 2);
    const float4 w0 = *reinterpret_cast<const float4*>(W + (lane * 2) * 4);
    const float4 w1 = *reinterpret_cast<const float4*>(W + (lane * 2 + 1) * 4);
    float a0 = xv.x * w0.x + xv.y * w1.x;
    float a1 = xv.x * w0.y + xv.y * w1.y;
    float a2 = xv.x * w0.z + xv.y * w1.z;
    float a3 = xv.x * w0.w + xv.y * w1.w;
#pragma unroll
    for (int m = 32; m >= 1; m >>= 1) {
        a0 += __shfl_xor(a0, m);
        a1 += __shfl_xor(a1, m);
        a2 += __shfl_xor(a2, m);
        a3 += __shfl_xor(a3, m);
    }
    if (lane == 0) {
        float di = dinv[node];
        *reinterpret_cast<float4*>(hs + (size_t)node * 4) =
            make_float4(a0 * di, a1 * di, a2 * di, a3 * di);
    }
}

template <int FOUT>
__global__ void k_gath_fin4(const int* __restrict__ rowoff, const int* __restrict__ csr,
                            const float* __restrict__ hs, const float* __restrict__ dinv,
                            const float* __restrict__ b, const float* __restrict__ Wn,
                            float* __restrict__ hsn, int n) {
    int gid = blockIdx.x * blockDim.x + threadIdx.x;
    int node = gid >> 6;
    int lane = threadIdx.x & 63;
    if (node >= n) return;
    int start = rowoff[node], end = rowoff[node + 1];
    float a0 = 0.f, a1 = 0.f, a2 = 0.f, a3 = 0.f;
    for (int j = start + lane; j < end; j += 64) {
        int s = csr[j];
        float4 v = *reinterpret_cast<const float4*>(hs + (size_t)s * 4);
        a0 += v.x; a1 += v.y; a2 += v.z; a3 += v.w;
    }
#pragma unroll
    for (int m = 32; m >= 1; m >>= 1) {
        a0 += __shfl_xor(a0, m);
        a1 += __shfl_xor(a1, m);
        a2 += __shfl_xor(a2, m);
        a3 += __shfl_xor(a3, m);
    }
    if (lane == 0) {
        float4 s = *reinterpret_cast<const float4*>(hs + (size_t)node * 4);
        float di = dinv[node];
        float h0 = tanhf((a0 + s.x) * di + b[0]);
        float h1 = tanhf((a1 + s.y) * di + b[1]);
        float h2 = tanhf((a2 + s.z) * di + b[2]);
        float h3 = tanhf((a3 + s.w) * di + b[3]);
        float o[FOUT];
#pragma unroll
        for (int j = 0; j < FOUT; j++) {
            o[j] = (h0 * Wn[0 * FOUT + j] + h1 * Wn[1 * FOUT + j] +
                    h2 * Wn[2 * FOUT + j] + h3 * Wn[3 * FOUT + j]) * di;
        }
        if constexpr (FOUT == 4) {
            *reinterpret_cast<float4*>(hsn + (size_t)node * 4) =
                make_float4(o[0], o[1], o[2], o[3]);
        } else {
            *reinterpret_cast<float2*>(hsn + (size_t)node * 2) = make_float2(o[0], o[1]);
        }
    }
}

__global__ void k_gath_fin3(const int* __restrict__ rowoff, const int* __restrict__ csr,
                            const float* __restrict__ hs, const float* __restrict__ dinv,
                            const float* __restrict__ b3, const float* __restrict__ Wc,
                            const float* __restrict__ bc, float* __restrict__ out,
                            float* __restrict__ hout, int n) {
    int gid = blockIdx.x * blockDim.x + threadIdx.x;
    int node = gid >> 6;
    int lane = threadIdx.x & 63;
    if (node >= n) return;
    int start = rowoff[node], end = rowoff[node + 1];
    float a0 = 0.f, a1 = 0.f;
    for (int j = start + lane; j < end; j += 64) {
        int s = csr[j];
        float2 v = *reinterpret_cast<const float2*>(hs + (size_t)s * 2);
        a0 += v.x; a1 += v.y;
    }
#pragma unroll
    for (int m = 32; m >= 1; m >>= 1) {
        a0 += __shfl_xor(a0, m);
        a1 += __shfl_xor(a1, m);
    }
    if (lane == 0) {
        float2 s = *reinterpret_cast<const float2*>(hs + (size_t)node * 2);
        float di = dinv[node];
        float h0 = tanhf((a0 + s.x) * di + b3[0]);
        float h1 = tanhf((a1 + s.y) * di + b3[1]);
        *reinterpret_cast<float2*>(hout + (size_t)node * 2) = make_float2(h0, h1);
        float4 o;
        o.x = h0 * Wc[0] + h1 * Wc[4] + bc[0];
        o.y = h0 * Wc[1] + h1 * Wc[5] + bc[1];
        o.z = h0 * Wc[2] + h1 * Wc[6] + bc[2];
        o.w = h0 * Wc[3] + h1 * Wc[7] + bc[3];
        *reinterpret_cast<float4*>(out + (size_t)node * 4) = o;
    }
}

extern "C" void kernel_launch(void* const* d_in, const int* in_sizes, int n_in,
                              void* d_out, int out_size, void* d_ws, size_t ws_size,
                              hipStream_t stream) {
    const float* x  = (const float*)d_in[0];
    const int*  ei  = (const int*)d_in[1];
    const float* W1 = (const float*)d_in[2];
    const float* b1 = (const float*)d_in[3];
    const float* W2 = (const float*)d_in[4];
    const float* b2 = (const float*)d_in[5];
    const float* W3 = (const float*)d_in[6];
    const float* b3 = (const float*)d_in[7];
    const float* Wc = (const float*)d_in[8];
    const float* bc = (const float*)d_in[9];

    const int n = in_sizes[0] / 128;
    const int e = in_sizes[1] / 2;
    const int* src = ei;
    const int* dst = ei + e;

    const int NBK = (n + 127) >> 7;              // 128-node buckets (782)

    const size_t MB = 1024 * 1024;
    char* ws = (char*)d_ws;
    float* dinv   = (float*)(ws + 0);                    // n floats
    float* hsA    = (float*)(ws + MB / 2);               // n*4 floats
    float* hsB    = (float*)(ws + 2 * MB + MB / 2);      // n*4 floats
    int*   rowoff = (int*)  (ws + 4 * MB + MB / 2);      // n+1 ints
    int*   btot   = (int*)  (ws + 5 * MB);               // NBK ints
    int*   bstart = (int*)  (ws + 5 * MB + 16 * 1024);   // NBK+1 ints
    int*   hbT    = (int*)  (ws + 5 * MB + MB / 2);      // NBK*G ints
    int*   loff   = (int*)  (ws + 8 * MB);               // G*NBK ints (new path)
    int*   packed = (int*)  (ws + 10 * MB + MB / 2);     // e ints (25.6 MB)
    int*   csr    = (int*)  (ws + 36 * MB + MB / 2);     // e ints (new path)

    float* out  = (float*)d_out;
    float* hout = out + (size_t)n * 4;

    const size_t need_new = 36 * MB + MB / 2 + (size_t)e * 4 + MB;
    const bool use_new = ws_size >= need_new;

    const int* csr_p;
    if (use_new) {
        const int G = (e + LCHUNK - 1) / LCHUNK;         // 391
        k_local<<<G, 512, 0, stream>>>(src, dst, packed, hbT, loff, NBK, G, e);
        k_scanA<<<NBK, 256, 0, stream>>>(hbT, btot, G);
        k_scanB<<<1, 512, 0, stream>>>(btot, bstart, NBK, e);
        k_merge<<<NBK, 256, 0, stream>>>(hbT, loff, btot, bstart, packed, csr,
                                         dinv, rowoff, NBK, G, n);
        csr_p = csr;
    } else {
        const int G2 = (e + CHUNK2 - 1) / CHUNK2;        // 400
        k_hist_o<<<G2, 512, 0, stream>>>(dst, hbT, NBK, G2, e);
        k_scanA<<<NBK, 256, 0, stream>>>(hbT, btot, G2);
        k_scanB<<<1, 512, 0, stream>>>(btot, bstart, NBK, e);
        k_part_o<<<G2, 512, 0, stream>>>(src, dst, hbT, bstart, packed, NBK, G2, e);
        k_build_o<<<NBK, 256, 0, stream>>>(bstart, packed, dinv, rowoff, n);
        csr_p = packed;
    }

    // Layer 1 GEMV: hsA = (x @ W1) * dinv
    const int wb = (n + 3) / 4;
    k_mm1<<<wb, 256, 0, stream>>>(x, W1, dinv, hsA, n);

    // Layers 1..3: owner-computes gather + fused finalize
    k_gath_fin4<4><<<wb, 256, 0, stream>>>(rowoff, csr_p, hsA, dinv, b1, W2, hsB, n);
    k_gath_fin4<2><<<wb, 256, 0, stream>>>(rowoff, csr_p, hsB, dinv, b2, W3, hsA, n);
    k_gath_fin3<<<wb, 256, 0, stream>>>(rowoff, csr_p, hsA, dinv, b3, Wc, bc, out, hout, n);

    (void)n_in; (void)out_size;
}

// Round 13
// 232.368 us; speedup vs baseline: 1.2542x; 1.0274x over previous
//
#include <hip/hip_runtime.h>
#include <math.h>

// GCN forward: 3x GCNConv (128->4->4->2) + classifier (2->4).
// Build pipeline: ZERO scattered global writes, ZERO global atomics:
//   k_local (1024 thr): per-16384-edge chunk LDS counting sort by 128-node
//            bucket -> coalesced sorted-chunk writeback + hbT + loff
//   scanA/scanB: per-bucket cross-chunk scan -> bstart
//   k_merge (512 thr): per-bucket gather of chunk runs (aligned int4 reads),
//            LDS counting sort by node -> coalesced CSR + rowoff + dinv
// Aggregation: owner-computes gather, wave per node, register reduce.
// r12 lesson: local/merge latency-bound at 21% occupancy (LDS-capped waves);
// widen to 32 waves/CU via 1024-thr local and 512-thr merge.

#define LCHUNK 16384
#define CHUNK2 16000   // fallback path chunk
#define MAXNB  1024    // 128-node buckets; n <= 131071
#define CAP    9600    // max edges per bucket (mean 8192, sigma~90 -> +15sig)

__device__ __forceinline__ int swz_chunk(int bid, int G) {
    if ((G & 7) != 0) return bid;
    return (bid & 7) * (G >> 3) + (bid >> 3);
}

// ---------- chunk-local counting sort (16384 edges, 16/thread, 1024 thr) --
__global__ __launch_bounds__(1024) void k_local(
        const int* __restrict__ src, const int* __restrict__ dst,
        int* __restrict__ packed, int* __restrict__ hbT, int* __restrict__ loff,
        int NBK, int G, int e) {
    __shared__ int hist[MAXNB];
    __shared__ int cur[MAXNB];
    __shared__ int part[1024];
    __shared__ int stage[LCHUNK];
    int g = blockIdx.x, tid = threadIdx.x;
    for (int b = tid; b < NBK; b += 1024) hist[b] = 0;
    __syncthreads();
    int i0 = g * LCHUNK;
    int i1 = min(i0 + LCHUNK, e);
    int val[16], bkt[16];
#pragma unroll
    for (int k = 0; k < 16; k++) {
        int i = i0 + tid + (k << 10);
        bool v = i < i1;
        int d = v ? dst[i] : 0;
        int s = v ? src[i] : 0;
        bkt[k] = v ? (d >> 7) : -1;
        val[k] = ((d & 127) << 17) | s;
        if (v) atomicAdd(&hist[d >> 7], 1);
    }
    __syncthreads();
    // block exclusive scan over NBK counts (1 bucket per thread; NBK<=1024)
    int s0 = (tid < NBK) ? hist[tid] : 0;
    part[tid] = s0;
    __syncthreads();
#pragma unroll
    for (int off = 1; off < 1024; off <<= 1) {
        int u = (tid >= off) ? part[tid - off] : 0;
        __syncthreads();
        part[tid] += u;
        __syncthreads();
    }
    int excl = part[tid] - s0;
    if (tid < NBK) {
        cur[tid] = excl;
        hbT[(size_t)tid * G + g] = s0;
        loff[(size_t)g * NBK + tid] = excl;
    }
    __syncthreads();
#pragma unroll
    for (int k = 0; k < 16; k++) {
        if (bkt[k] >= 0) {
            int p = atomicAdd(&cur[bkt[k]], 1);
            stage[p] = val[k];
        }
    }
    __syncthreads();
    int len = i1 - i0;
    for (int i = tid; i < len; i += 1024)
        packed[i0 + i] = stage[i];
}

// Per-bucket exclusive scan over chunks (block per bucket, contiguous row).
__global__ void k_scanA(int* __restrict__ hbT, int* __restrict__ btot, int G) {
    __shared__ int part[256];
    int b = blockIdx.x, t = threadIdx.x;
    int* row = hbT + (size_t)b * G;
    int C = (G + 255) / 256;
    int lo = t * C, hi = min(lo + C, G);
    int s = 0;
    for (int i = lo; i < hi; i++) s += row[i];
    part[t] = s;
    __syncthreads();
#pragma unroll
    for (int off = 1; off < 256; off <<= 1) {
        int u = (t >= off) ? part[t - off] : 0;
        __syncthreads();
        part[t] += u;
        __syncthreads();
    }
    int run = part[t] - s;
    for (int i = lo; i < hi; i++) {
        int v = row[i];
        row[i] = run;
        run += v;
    }
    if (t == 255) btot[b] = part[255];
}

__global__ void k_scanB(const int* __restrict__ btot, int* __restrict__ bstart,
                        int NB, int e) {
    __shared__ int part[512];
    int t = threadIdx.x;
    int C = (NB + 511) / 512;
    int lo = t * C, hi = min(lo + C, NB);
    int s = 0;
    for (int i = lo; i < hi; i++) s += btot[i];
    part[t] = s;
    __syncthreads();
#pragma unroll
    for (int off = 1; off < 512; off <<= 1) {
        int u = (t >= off) ? part[t - off] : 0;
        __syncthreads();
        part[t] += u;
        __syncthreads();
    }
    int run = part[t] - s;
    for (int i = lo; i < hi; i++) {
        bstart[i] = run;
        run += btot[i];
    }
    if (t == 511) bstart[NB] = e;
}

// Merge runs of one bucket (aligned int4 reads), counting-sort by node,
// emit CSR + rowoff + dinv. 512 threads.
__global__ __launch_bounds__(512) void k_merge(
        const int* __restrict__ hbT, const int* __restrict__ loff,
        const int* __restrict__ btot, const int* __restrict__ bstart,
        const int* __restrict__ packed, int* __restrict__ csr,
        float* __restrict__ dinv, int* __restrict__ rowoff,
        int NBK, int G, int n) {
    __shared__ int stage[CAP];
    __shared__ int cnt[128];
    __shared__ int off[128];
    __shared__ int cur[128];
    int b = blockIdx.x, tid = threadIdx.x;
    int btt = btot[b];
    int total = min(btt, CAP);
    for (int g = tid; g < G; g += 512) {
        int o  = hbT[(size_t)b * G + g];
        int nx = (g + 1 < G) ? hbT[(size_t)b * G + g + 1] : btt;
        if (nx > CAP) nx = CAP;
        if (o >= nx) continue;
        int len = nx - o;
        int sp = g * LCHUNK + loff[(size_t)g * NBK + b];
        int a   = sp & ~3;
        int rel = sp - a;                  // 0..3
        int n4  = (rel + len + 3) >> 2;
        for (int q = 0; q < n4; q++) {
            int4 w = *reinterpret_cast<const int4*>(packed + a + q * 4);
            int base = q * 4 - rel;        // index of w.x within run
            if (base >= 0 && base < len)     stage[o + base]     = w.x;
            if (base + 1 >= 0 && base + 1 < len) stage[o + base + 1] = w.y;
            if (base + 2 >= 0 && base + 2 < len) stage[o + base + 2] = w.z;
            if (base + 3 >= 0 && base + 3 < len) stage[o + base + 3] = w.w;
        }
    }
    if (tid < 128) cnt[tid] = 0;
    __syncthreads();
    for (int i = tid; i < total; i += 512) atomicAdd(&cnt[stage[i] >> 17], 1);
    __syncthreads();
    if (tid < 128) off[tid] = cnt[tid];
    __syncthreads();
#pragma unroll
    for (int s = 1; s < 128; s <<= 1) {
        int v = 0;
        if (tid < 128 && tid >= s) v = off[tid - s];
        __syncthreads();
        if (tid < 128 && tid >= s) off[tid] += v;
        __syncthreads();
    }
    if (tid < 128) {
        int excl = off[tid] - cnt[tid];
        int node = (b << 7) + tid;
        if (node < n) dinv[node] = 1.0f / sqrtf((float)(cnt[tid] + 1));
        if (node <= n) rowoff[node] = bstart[b] + excl;
        cur[tid] = excl;
    }
    __syncthreads();
    int base = bstart[b];
    for (int i = tid; i < total; i += 512) {
        int w = stage[i];
        int p = atomicAdd(&cur[w >> 17], 1);
        csr[base + p] = w & 0x1FFFF;
    }
}

// ---------- fallback path (r9): global-scatter partition ----------
__global__ void k_hist_o(const int* __restrict__ dst, int* __restrict__ hbT,
                         int NB, int G, int e) {
    __shared__ int hist[MAXNB];
    int g = swz_chunk(blockIdx.x, G);
    for (int b = threadIdx.x; b < NB; b += 512) hist[b] = 0;
    __syncthreads();
    long long i0 = (long long)g * CHUNK2;
    int i1 = (int)min(i0 + CHUNK2, (long long)e);
    for (int i = (int)i0 + threadIdx.x; i < i1; i += 512)
        atomicAdd(&hist[dst[i] >> 7], 1);
    __syncthreads();
    for (int b = threadIdx.x; b < NB; b += 512)
        hbT[(size_t)b * G + g] = hist[b];
}

__global__ void k_part_o(const int* __restrict__ src, const int* __restrict__ dst,
                         const int* __restrict__ hbT, const int* __restrict__ bstart,
                         int* __restrict__ packed, int NB, int G, int e) {
    __shared__ int cur[MAXNB];
    int g = swz_chunk(blockIdx.x, G);
    for (int b = threadIdx.x; b < NB; b += 512)
        cur[b] = hbT[(size_t)b * G + g] + bstart[b];
    __syncthreads();
    long long i0 = (long long)g * CHUNK2;
    int i1 = (int)min(i0 + CHUNK2, (long long)e);
    for (int i = (int)i0 + threadIdx.x; i < i1; i += 512) {
        int d = dst[i], s = src[i];
        int pos = atomicAdd(&cur[d >> 7], 1);
        packed[pos] = ((d & 127) << 17) | s;
    }
}

__global__ void k_build_o(const int* __restrict__ bstart, int* __restrict__ packed,
                          float* __restrict__ dinv, int* __restrict__ rowoff, int n) {
    __shared__ int stage[CAP];
    __shared__ int cnt[128];
    __shared__ int off[128];
    __shared__ int cur[128];
    int b = blockIdx.x, tid = threadIdx.x;
    int lo = bstart[b];
    int len = bstart[b + 1] - lo;
    if (len > CAP) len = CAP;
    if (tid < 128) cnt[tid] = 0;
    for (int i = tid; i < len; i += 256) stage[i] = packed[lo + i];
    __syncthreads();
    for (int i = tid; i < len; i += 256) atomicAdd(&cnt[stage[i] >> 17], 1);
    __syncthreads();
    if (tid < 128) off[tid] = cnt[tid];
    __syncthreads();
#pragma unroll
    for (int s = 1; s < 128; s <<= 1) {
        int v = 0;
        if (tid < 128 && tid >= s) v = off[tid - s];
        __syncthreads();
        if (tid < 128 && tid >= s) off[tid] += v;
        __syncthreads();
    }
    if (tid < 128) {
        int excl = off[tid] - cnt[tid];
        int node = (b << 7) + tid;
        if (node < n) dinv[node] = 1.0f / sqrtf((float)(cnt[tid] + 1));
        if (node <= n) rowoff[node] = lo + excl;
        cur[tid] = excl;
    }
    __syncthreads();
    for (int i = tid; i < len; i += 256) {
        int w = stage[i];
        int p = atomicAdd(&cur[w >> 17], 1);
        packed[lo + p] = w & 0x1FFFF;
    }
}

// ---------- compute kernels ----------
__global__ void k_mm1(const float* __restrict__ x, const float* __restrict__ W,
                      const float* __restrict__ dinv, float* __restrict__ hs, int n) {
    int gid = blockIdx.x * blockDim.x + threadIdx.x;
    int node = gid >> 6;
    int lane = threadIdx.x & 63;
    if (node >= n) return;
    const float2 xv = *reinterpret_cast<const float2*>(x + (size_t)node * 128 + lane * 2);
    const float4 w0 = *reinterpret_cast<const float4*>(W + (lane * 2) * 4);
    const float4 w1 = *reinterpret_cast<const float4*>(W + (lane * 2 + 1) * 4);
    float a0 = xv.x * w0.x + xv.y * w1.x;
    float a1 = xv.x * w0.y + xv.y * w1.y;
    float a2 = xv.x * w0.z + xv.y * w1.z;
    float a3 = xv.x * w0.w + xv.y * w1.w;
#pragma unroll
    for (int m = 32; m >= 1; m >>= 1) {
        a0 += __shfl_xor(a0, m);
        a1 += __shfl_xor(a1, m);
        a2 += __shfl_xor(a2, m);
        a3 += __shfl_xor(a3, m);
    }
    if (lane == 0) {
        float di = dinv[node];
        *reinterpret_cast<float4*>(hs + (size_t)node * 4) =
            make_float4(a0 * di, a1 * di, a2 * di, a3 * di);
    }
}

template <int FOUT>
__global__ void k_gath_fin4(const int* __restrict__ rowoff, const int* __restrict__ csr,
                            const float* __restrict__ hs, const float* __restrict__ dinv,
                            const float* __restrict__ b, const float* __restrict__ Wn,
                            float* __restrict__ hsn, int n) {
    int gid = blockIdx.x * blockDim.x + threadIdx.x;
    int node = gid >> 6;
    int lane = threadIdx.x & 63;
    if (node >= n) return;
    int start = rowoff[node], end = rowoff[node + 1];
    float a0 = 0.f, a1 = 0.f, a2 = 0.f, a3 = 0.f;
    for (int j = start + lane; j < end; j += 64) {
        int s = csr[j];
        float4 v = *reinterpret_cast<const float4*>(hs + (size_t)s * 4);
        a0 += v.x; a1 += v.y; a2 += v.z; a3 += v.w;
    }
#pragma unroll
    for (int m = 32; m >= 1; m >>= 1) {
        a0 += __shfl_xor(a0, m);
        a1 += __shfl_xor(a1, m);
        a2 += __shfl_xor(a2, m);
        a3 += __shfl_xor(a3, m);
    }
    if (lane == 0) {
        float4 s = *reinterpret_cast<const float4*>(hs + (size_t)node * 4);
        float di = dinv[node];
        float h0 = tanhf((a0 + s.x) * di + b[0]);
        float h1 = tanhf((a1 + s.y) * di + b[1]);
        float h2 = tanhf((a2 + s.z) * di + b[2]);
        float h3 = tanhf((a3 + s.w) * di + b[3]);
        float o[FOUT];
#pragma unroll
        for (int j = 0; j < FOUT; j++) {
            o[j] = (h0 * Wn[0 * FOUT + j] + h1 * Wn[1 * FOUT + j] +
                    h2 * Wn[2 * FOUT + j] + h3 * Wn[3 * FOUT + j]) * di;
        }
        if constexpr (FOUT == 4) {
            *reinterpret_cast<float4*>(hsn + (size_t)node * 4) =
                make_float4(o[0], o[1], o[2], o[3]);
        } else {
            *reinterpret_cast<float2*>(hsn + (size_t)node * 2) = make_float2(o[0], o[1]);
        }
    }
}

__global__ void k_gath_fin3(const int* __restrict__ rowoff, const int* __restrict__ csr,
                            const float* __restrict__ hs, const float* __restrict__ dinv,
                            const float* __restrict__ b3, const float* __restrict__ Wc,
                            const float* __restrict__ bc, float* __restrict__ out,
                            float* __restrict__ hout, int n) {
    int gid = blockIdx.x * blockDim.x + threadIdx.x;
    int node = gid >> 6;
    int lane = threadIdx.x & 63;
    if (node >= n) return;
    int start = rowoff[node], end = rowoff[node + 1];
    float a0 = 0.f, a1 = 0.f;
    for (int j = start + lane; j < end; j += 64) {
        int s = csr[j];
        float2 v = *reinterpret_cast<const float2*>(hs + (size_t)s * 2);
        a0 += v.x; a1 += v.y;
    }
#pragma unroll
    for (int m = 32; m >= 1; m >>= 1) {
        a0 += __shfl_xor(a0, m);
        a1 += __shfl_xor(a1, m);
    }
    if (lane == 0) {
        float2 s = *reinterpret_cast<const float2*>(hs + (size_t)node * 2);
        float di = dinv[node];
        float h0 = tanhf((a0 + s.x) * di + b3[0]);
        float h1 = tanhf((a1 + s.y) * di + b3[1]);
        *reinterpret_cast<float2*>(hout + (size_t)node * 2) = make_float2(h0, h1);
        float4 o;
        o.x = h0 * Wc[0] + h1 * Wc[4] + bc[0];
        o.y = h0 * Wc[1] + h1 * Wc[5] + bc[1];
        o.z = h0 * Wc[2] + h1 * Wc[6] + bc[2];
        o.w = h0 * Wc[3] + h1 * Wc[7] + bc[3];
        *reinterpret_cast<float4*>(out + (size_t)node * 4) = o;
    }
}

extern "C" void kernel_launch(void* const* d_in, const int* in_sizes, int n_in,
                              void* d_out, int out_size, void* d_ws, size_t ws_size,
                              hipStream_t stream) {
    const float* x  = (const float*)d_in[0];
    const int*  ei  = (const int*)d_in[1];
    const float* W1 = (const float*)d_in[2];
    const float* b1 = (const float*)d_in[3];
    const float* W2 = (const float*)d_in[4];
    const float* b2 = (const float*)d_in[5];
    const float* W3 = (const float*)d_in[6];
    const float* b3 = (const float*)d_in[7];
    const float* Wc = (const float*)d_in[8];
    const float* bc = (const float*)d_in[9];

    const int n = in_sizes[0] / 128;
    const int e = in_sizes[1] / 2;
    const int* src = ei;
    const int* dst = ei + e;

    const int NBK = (n + 127) >> 7;              // 128-node buckets (782)

    const size_t MB = 1024 * 1024;
    char* ws = (char*)d_ws;
    float* dinv   = (float*)(ws + 0);                    // n floats
    float* hsA    = (float*)(ws + MB / 2);               // n*4 floats
    float* hsB    = (float*)(ws + 2 * MB + MB / 2);      // n*4 floats
    int*   rowoff = (int*)  (ws + 4 * MB + MB / 2);      // n+1 ints
    int*   btot   = (int*)  (ws + 5 * MB);               // NBK ints
    int*   bstart = (int*)  (ws + 5 * MB + 16 * 1024);   // NBK+1 ints
    int*   hbT    = (int*)  (ws + 5 * MB + MB / 2);      // NBK*G ints
    int*   loff   = (int*)  (ws + 8 * MB);               // G*NBK ints (new path)
    int*   packed = (int*)  (ws + 10 * MB + MB / 2);     // e ints (25.6 MB)
    int*   csr    = (int*)  (ws + 36 * MB + MB / 2);     // e ints (new path)

    float* out  = (float*)d_out;
    float* hout = out + (size_t)n * 4;

    const size_t need_new = 36 * MB + MB / 2 + (size_t)e * 4 + MB;
    const bool use_new = ws_size >= need_new;

    const int* csr_p;
    if (use_new) {
        const int G = (e + LCHUNK - 1) / LCHUNK;         // 391
        k_local<<<G, 1024, 0, stream>>>(src, dst, packed, hbT, loff, NBK, G, e);
        k_scanA<<<NBK, 256, 0, stream>>>(hbT, btot, G);
        k_scanB<<<1, 512, 0, stream>>>(btot, bstart, NBK, e);
        k_merge<<<NBK, 512, 0, stream>>>(hbT, loff, btot, bstart, packed, csr,
                                         dinv, rowoff, NBK, G, n);
        csr_p = csr;
    } else {
        const int G2 = (e + CHUNK2 - 1) / CHUNK2;        // 400
        k_hist_o<<<G2, 512, 0, stream>>>(dst, hbT, NBK, G2, e);
        k_scanA<<<NBK, 256, 0, stream>>>(hbT, btot, G2);
        k_scanB<<<1, 512, 0, stream>>>(btot, bstart, NBK, e);
        k_part_o<<<G2, 512, 0, stream>>>(src, dst, hbT, bstart, packed, NBK, G2, e);
        k_build_o<<<NBK, 256, 0, stream>>>(bstart, packed, dinv, rowoff, n);
        csr_p = packed;
    }

    // Layer 1 GEMV: hsA = (x @ W1) * dinv
    const int wb = (n + 3) / 4;
    k_mm1<<<wb, 256, 0, stream>>>(x, W1, dinv, hsA, n);

    // Layers 1..3: owner-computes gather + fused finalize
    k_gath_fin4<4><<<wb, 256, 0, stream>>>(rowoff, csr_p, hsA, dinv, b1, W2, hsB, n);
    k_gath_fin4<2><<<wb, 256, 0, stream>>>(rowoff, csr_p, hsB, dinv, b2, W3, hsA, n);
    k_gath_fin3<<<wb, 256, 0, stream>>>(rowoff, csr_p, hsA, dinv, b3, Wc, bc, out, hout, n);

    (void)n_in; (void)out_size;
}

// Round 14
// 229.116 us; speedup vs baseline: 1.2720x; 1.0142x over previous
//
#include <hip/hip_runtime.h>
#include <math.h>

// GCN forward: 3x GCNConv (128->4->4->2) + classifier (2->4).
// Build pipeline: ZERO scattered global writes, ZERO global atomics:
//   k_local (1024 thr): per-16384-edge chunk LDS counting sort by 256-node
//            bucket -> coalesced sorted-chunk writeback + hbT + loff
//   scanA/scanB: per-bucket cross-chunk scan -> bstart
//   k_merge (512 thr): per-bucket gather of chunk runs (aligned int4 reads),
//            LDS counting sort by node -> coalesced CSR + rowoff + dinv
// Aggregation: owner-computes gather, wave per node, register reduce.
// r13 lesson: merge is HBM random-line-fetch bound (occupancy-insensitive);
// 256-node buckets halve run count (runs ~42 edges = 168B).

#define LCHUNK 16384
#define CHUNK2 16000   // fallback path chunk
#define MAXNB  512     // 256-node buckets; n <= 131071
#define CAP    18432   // max edges per bucket (mean 16368, sigma~128 -> +16s)
#define MAXNB2 1024    // fallback: 128-node buckets
#define CAP2   9600    // fallback bucket cap

__device__ __forceinline__ int swz_chunk(int bid, int G) {
    if ((G & 7) != 0) return bid;
    return (bid & 7) * (G >> 3) + (bid >> 3);
}

// ---------- chunk-local counting sort (16384 edges, 16/thread, 1024 thr) --
__global__ __launch_bounds__(1024) void k_local(
        const int* __restrict__ src, const int* __restrict__ dst,
        int* __restrict__ packed, int* __restrict__ hbT, int* __restrict__ loff,
        int NBK, int G, int e) {
    __shared__ int hist[MAXNB];
    __shared__ int cur[MAXNB];
    __shared__ int part[1024];
    __shared__ int stage[LCHUNK];
    int g = blockIdx.x, tid = threadIdx.x;
    for (int b = tid; b < NBK; b += 1024) hist[b] = 0;
    __syncthreads();
    int i0 = g * LCHUNK;
    int i1 = min(i0 + LCHUNK, e);
    int val[16], bkt[16];
#pragma unroll
    for (int k = 0; k < 16; k++) {
        int i = i0 + tid + (k << 10);
        bool v = i < i1;
        int d = v ? dst[i] : 0;
        int s = v ? src[i] : 0;
        bkt[k] = v ? (d >> 8) : -1;
        val[k] = ((d & 255) << 17) | s;
        if (v) atomicAdd(&hist[d >> 8], 1);
    }
    __syncthreads();
    // block exclusive scan over NBK counts (1 bucket per thread; NBK<=1024)
    int s0 = (tid < NBK) ? hist[tid] : 0;
    part[tid] = s0;
    __syncthreads();
#pragma unroll
    for (int off = 1; off < 1024; off <<= 1) {
        int u = (tid >= off) ? part[tid - off] : 0;
        __syncthreads();
        part[tid] += u;
        __syncthreads();
    }
    int excl = part[tid] - s0;
    if (tid < NBK) {
        cur[tid] = excl;
        hbT[(size_t)tid * G + g] = s0;
        loff[(size_t)g * NBK + tid] = excl;
    }
    __syncthreads();
#pragma unroll
    for (int k = 0; k < 16; k++) {
        if (bkt[k] >= 0) {
            int p = atomicAdd(&cur[bkt[k]], 1);
            stage[p] = val[k];
        }
    }
    __syncthreads();
    int len = i1 - i0;
    for (int i = tid; i < len; i += 1024)
        packed[i0 + i] = stage[i];
}

// Per-bucket exclusive scan over chunks (block per bucket, contiguous row).
__global__ void k_scanA(int* __restrict__ hbT, int* __restrict__ btot, int G) {
    __shared__ int part[256];
    int b = blockIdx.x, t = threadIdx.x;
    int* row = hbT + (size_t)b * G;
    int C = (G + 255) / 256;
    int lo = t * C, hi = min(lo + C, G);
    int s = 0;
    for (int i = lo; i < hi; i++) s += row[i];
    part[t] = s;
    __syncthreads();
#pragma unroll
    for (int off = 1; off < 256; off <<= 1) {
        int u = (t >= off) ? part[t - off] : 0;
        __syncthreads();
        part[t] += u;
        __syncthreads();
    }
    int run = part[t] - s;
    for (int i = lo; i < hi; i++) {
        int v = row[i];
        row[i] = run;
        run += v;
    }
    if (t == 255) btot[b] = part[255];
}

__global__ void k_scanB(const int* __restrict__ btot, int* __restrict__ bstart,
                        int NB, int e) {
    __shared__ int part[512];
    int t = threadIdx.x;
    int C = (NB + 511) / 512;
    int lo = t * C, hi = min(lo + C, NB);
    int s = 0;
    for (int i = lo; i < hi; i++) s += btot[i];
    part[t] = s;
    __syncthreads();
#pragma unroll
    for (int off = 1; off < 512; off <<= 1) {
        int u = (t >= off) ? part[t - off] : 0;
        __syncthreads();
        part[t] += u;
        __syncthreads();
    }
    int run = part[t] - s;
    for (int i = lo; i < hi; i++) {
        bstart[i] = run;
        run += btot[i];
    }
    if (t == 511) bstart[NB] = e;
}

// Merge runs of one 256-node bucket (aligned int4 reads), counting-sort by
// node, emit CSR + rowoff + dinv. 512 threads, ~77KB LDS (2 blocks/CU).
__global__ __launch_bounds__(512) void k_merge(
        const int* __restrict__ hbT, const int* __restrict__ loff,
        const int* __restrict__ btot, const int* __restrict__ bstart,
        const int* __restrict__ packed, int* __restrict__ csr,
        float* __restrict__ dinv, int* __restrict__ rowoff,
        int NBK, int G, int n) {
    __shared__ int stage[CAP];
    __shared__ int cnt[256];
    __shared__ int off[256];
    __shared__ int cur[256];
    int b = blockIdx.x, tid = threadIdx.x;
    int btt = btot[b];
    int total = min(btt, CAP);
    for (int g = tid; g < G; g += 512) {
        int o  = hbT[(size_t)b * G + g];
        int nx = (g + 1 < G) ? hbT[(size_t)b * G + g + 1] : btt;
        if (nx > CAP) nx = CAP;
        if (o >= nx) continue;
        int len = nx - o;
        int sp = g * LCHUNK + loff[(size_t)g * NBK + b];
        int a   = sp & ~3;
        int rel = sp - a;                  // 0..3
        int n4  = (rel + len + 3) >> 2;
        for (int q = 0; q < n4; q++) {
            int4 w = *reinterpret_cast<const int4*>(packed + a + q * 4);
            int base = q * 4 - rel;        // index of w.x within run
            if (base >= 0 && base < len)     stage[o + base]     = w.x;
            if (base + 1 >= 0 && base + 1 < len) stage[o + base + 1] = w.y;
            if (base + 2 >= 0 && base + 2 < len) stage[o + base + 2] = w.z;
            if (base + 3 >= 0 && base + 3 < len) stage[o + base + 3] = w.w;
        }
    }
    if (tid < 256) cnt[tid] = 0;
    __syncthreads();
    for (int i = tid; i < total; i += 512) atomicAdd(&cnt[stage[i] >> 17], 1);
    __syncthreads();
    if (tid < 256) off[tid] = cnt[tid];
    __syncthreads();
#pragma unroll
    for (int s = 1; s < 256; s <<= 1) {
        int v = 0;
        if (tid < 256 && tid >= s) v = off[tid - s];
        __syncthreads();
        if (tid < 256 && tid >= s) off[tid] += v;
        __syncthreads();
    }
    if (tid < 256) {
        int excl = off[tid] - cnt[tid];
        int node = (b << 8) + tid;
        if (node < n) dinv[node] = 1.0f / sqrtf((float)(cnt[tid] + 1));
        if (node <= n) rowoff[node] = bstart[b] + excl;
        cur[tid] = excl;
    }
    __syncthreads();
    int base = bstart[b];
    for (int i = tid; i < total; i += 512) {
        int w = stage[i];
        int p = atomicAdd(&cur[w >> 17], 1);
        csr[base + p] = w & 0x1FFFF;
    }
}

// ---------- fallback path (r9): global-scatter partition, 128-buckets ----
__global__ void k_hist_o(const int* __restrict__ dst, int* __restrict__ hbT,
                         int NB, int G, int e) {
    __shared__ int hist[MAXNB2];
    int g = swz_chunk(blockIdx.x, G);
    for (int b = threadIdx.x; b < NB; b += 512) hist[b] = 0;
    __syncthreads();
    long long i0 = (long long)g * CHUNK2;
    int i1 = (int)min(i0 + CHUNK2, (long long)e);
    for (int i = (int)i0 + threadIdx.x; i < i1; i += 512)
        atomicAdd(&hist[dst[i] >> 7], 1);
    __syncthreads();
    for (int b = threadIdx.x; b < NB; b += 512)
        hbT[(size_t)b * G + g] = hist[b];
}

__global__ void k_part_o(const int* __restrict__ src, const int* __restrict__ dst,
                         const int* __restrict__ hbT, const int* __restrict__ bstart,
                         int* __restrict__ packed, int NB, int G, int e) {
    __shared__ int cur[MAXNB2];
    int g = swz_chunk(blockIdx.x, G);
    for (int b = threadIdx.x; b < NB; b += 512)
        cur[b] = hbT[(size_t)b * G + g] + bstart[b];
    __syncthreads();
    long long i0 = (long long)g * CHUNK2;
    int i1 = (int)min(i0 + CHUNK2, (long long)e);
    for (int i = (int)i0 + threadIdx.x; i < i1; i += 512) {
        int d = dst[i], s = src[i];
        int pos = atomicAdd(&cur[d >> 7], 1);
        packed[pos] = ((d & 127) << 17) | s;
    }
}

__global__ void k_build_o(const int* __restrict__ bstart, int* __restrict__ packed,
                          float* __restrict__ dinv, int* __restrict__ rowoff, int n) {
    __shared__ int stage[CAP2];
    __shared__ int cnt[128];
    __shared__ int off[128];
    __shared__ int cur[128];
    int b = blockIdx.x, tid = threadIdx.x;
    int lo = bstart[b];
    int len = bstart[b + 1] - lo;
    if (len > CAP2) len = CAP2;
    if (tid < 128) cnt[tid] = 0;
    for (int i = tid; i < len; i += 256) stage[i] = packed[lo + i];
    __syncthreads();
    for (int i = tid; i < len; i += 256) atomicAdd(&cnt[stage[i] >> 17], 1);
    __syncthreads();
    if (tid < 128) off[tid] = cnt[tid];
    __syncthreads();
#pragma unroll
    for (int s = 1; s < 128; s <<= 1) {
        int v = 0;
        if (tid < 128 && tid >= s) v = off[tid - s];
        __syncthreads();
        if (tid < 128 && tid >= s) off[tid] += v;
        __syncthreads();
    }
    if (tid < 128) {
        int excl = off[tid] - cnt[tid];
        int node = (b << 7) + tid;
        if (node < n) dinv[node] = 1.0f / sqrtf((float)(cnt[tid] + 1));
        if (node <= n) rowoff[node] = lo + excl;
        cur[tid] = excl;
    }
    __syncthreads();
    for (int i = tid; i < len; i += 256) {
        int w = stage[i];
        int p = atomicAdd(&cur[w >> 17], 1);
        packed[lo + p] = w & 0x1FFFF;
    }
}

// ---------- compute kernels ----------
__global__ void k_mm1(const float* __restrict__ x, const float* __restrict__ W,
                      const float* __restrict__ dinv, float* __restrict__ hs, int n) {
    int gid = blockIdx.x * blockDim.x + threadIdx.x;
    int node = gid >> 6;
    int lane = threadIdx.x & 63;
    if (node >= n) return;
    const float2 xv = *reinterpret_cast<const float2*>(x + (size_t)node * 128 + lane * 2);
    const float4 w0 = *reinterpret_cast<const float4*>(W + (lane * 2) * 4);
    const float4 w1 = *reinterpret_cast<const float4*>(W + (lane * 2 + 1) * 4);
    float a0 = xv.x * w0.x + xv.y * w1.x;
    float a1 = xv.x * w0.y + xv.y * w1.y;
    float a2 = xv.x * w0.z + xv.y * w1.z;
    float a3 = xv.x * w0.w + xv.y * w1.w;
#pragma unroll
    for (int m = 32; m >= 1; m >>= 1) {
        a0 += __shfl_xor(a0, m);
        a1 += __shfl_xor(a1, m);
        a2 += __shfl_xor(a2, m);
        a3 += __shfl_xor(a3, m);
    }
    if (lane == 0) {
        float di = dinv[node];
        *reinterpret_cast<float4*>(hs + (size_t)node * 4) =
            make_float4(a0 * di, a1 * di, a2 * di, a3 * di);
    }
}

template <int FOUT>
__global__ void k_gath_fin4(const int* __restrict__ rowoff, const int* __restrict__ csr,
                            const float* __restrict__ hs, const float* __restrict__ dinv,
                            const float* __restrict__ b, const float* __restrict__ Wn,
                            float* __restrict__ hsn, int n) {
    int gid = blockIdx.x * blockDim.x + threadIdx.x;
    int node = gid >> 6;
    int lane = threadIdx.x & 63;
    if (node >= n) return;
    int start = rowoff[node], end = rowoff[node + 1];
    float a0 = 0.f, a1 = 0.f, a2 = 0.f, a3 = 0.f;
    for (int j = start + lane; j < end; j += 64) {
        int s = csr[j];
        float4 v = *reinterpret_cast<const float4*>(hs + (size_t)s * 4);
        a0 += v.x; a1 += v.y; a2 += v.z; a3 += v.w;
    }
#pragma unroll
    for (int m = 32; m >= 1; m >>= 1) {
        a0 += __shfl_xor(a0, m);
        a1 += __shfl_xor(a1, m);
        a2 += __shfl_xor(a2, m);
        a3 += __shfl_xor(a3, m);
    }
    if (lane == 0) {
        float4 s = *reinterpret_cast<const float4*>(hs + (size_t)node * 4);
        float di = dinv[node];
        float h0 = tanhf((a0 + s.x) * di + b[0]);
        float h1 = tanhf((a1 + s.y) * di + b[1]);
        float h2 = tanhf((a2 + s.z) * di + b[2]);
        float h3 = tanhf((a3 + s.w) * di + b[3]);
        float o[FOUT];
#pragma unroll
        for (int j = 0; j < FOUT; j++) {
            o[j] = (h0 * Wn[0 * FOUT + j] + h1 * Wn[1 * FOUT + j] +
                    h2 * Wn[2 * FOUT + j] + h3 * Wn[3 * FOUT + j]) * di;
        }
        if constexpr (FOUT == 4) {
            *reinterpret_cast<float4*>(hsn + (size_t)node * 4) =
                make_float4(o[0], o[1], o[2], o[3]);
        } else {
            *reinterpret_cast<float2*>(hsn + (size_t)node * 2) = make_float2(o[0], o[1]);
        }
    }
}

__global__ void k_gath_fin3(const int* __restrict__ rowoff, const int* __restrict__ csr,
                            const float* __restrict__ hs, const float* __restrict__ dinv,
                            const float* __restrict__ b3, const float* __restrict__ Wc,
                            const float* __restrict__ bc, float* __restrict__ out,
                            float* __restrict__ hout, int n) {
    int gid = blockIdx.x * blockDim.x + threadIdx.x;
    int node = gid >> 6;
    int lane = threadIdx.x & 63;
    if (node >= n) return;
    int start = rowoff[node], end = rowoff[node + 1];
    float a0 = 0.f, a1 = 0.f;
    for (int j = start + lane; j < end; j += 64) {
        int s = csr[j];
        float2 v = *reinterpret_cast<const float2*>(hs + (size_t)s * 2);
        a0 += v.x; a1 += v.y;
    }
#pragma unroll
    for (int m = 32; m >= 1; m >>= 1) {
        a0 += __shfl_xor(a0, m);
        a1 += __shfl_xor(a1, m);
    }
    if (lane == 0) {
        float2 s = *reinterpret_cast<const float2*>(hs + (size_t)node * 2);
        float di = dinv[node];
        float h0 = tanhf((a0 + s.x) * di + b3[0]);
        float h1 = tanhf((a1 + s.y) * di + b3[1]);
        *reinterpret_cast<float2*>(hout + (size_t)node * 2) = make_float2(h0, h1);
        float4 o;
        o.x = h0 * Wc[0] + h1 * Wc[4] + bc[0];
        o.y = h0 * Wc[1] + h1 * Wc[5] + bc[1];
        o.z = h0 * Wc[2] + h1 * Wc[6] + bc[2];
        o.w = h0 * Wc[3] + h1 * Wc[7] + bc[3];
        *reinterpret_cast<float4*>(out + (size_t)node * 4) = o;
    }
}

extern "C" void kernel_launch(void* const* d_in, const int* in_sizes, int n_in,
                              void* d_out, int out_size, void* d_ws, size_t ws_size,
                              hipStream_t stream) {
    const float* x  = (const float*)d_in[0];
    const int*  ei  = (const int*)d_in[1];
    const float* W1 = (const float*)d_in[2];
    const float* b1 = (const float*)d_in[3];
    const float* W2 = (const float*)d_in[4];
    const float* b2 = (const float*)d_in[5];
    const float* W3 = (const float*)d_in[6];
    const float* b3 = (const float*)d_in[7];
    const float* Wc = (const float*)d_in[8];
    const float* bc = (const float*)d_in[9];

    const int n = in_sizes[0] / 128;
    const int e = in_sizes[1] / 2;
    const int* src = ei;
    const int* dst = ei + e;

    const size_t MB = 1024 * 1024;
    char* ws = (char*)d_ws;
    float* dinv   = (float*)(ws + 0);                    // n floats
    float* hsA    = (float*)(ws + MB / 2);               // n*4 floats
    float* hsB    = (float*)(ws + 2 * MB + MB / 2);      // n*4 floats
    int*   rowoff = (int*)  (ws + 4 * MB + MB / 2);      // n+1 ints
    int*   btot   = (int*)  (ws + 5 * MB);               // NBK ints
    int*   bstart = (int*)  (ws + 5 * MB + 16 * 1024);   // NBK+1 ints
    int*   hbT    = (int*)  (ws + 5 * MB + MB / 2);      // NBK*G ints
    int*   loff   = (int*)  (ws + 8 * MB);               // G*NBK ints (new path)
    int*   packed = (int*)  (ws + 10 * MB + MB / 2);     // e ints (25.6 MB)
    int*   csr    = (int*)  (ws + 36 * MB + MB / 2);     // e ints (new path)

    float* out  = (float*)d_out;
    float* hout = out + (size_t)n * 4;

    const size_t need_new = 36 * MB + MB / 2 + (size_t)e * 4 + MB;
    const bool use_new = ws_size >= need_new;

    const int* csr_p;
    if (use_new) {
        const int NBK = (n + 255) >> 8;                  // 391
        const int G = (e + LCHUNK - 1) / LCHUNK;         // 391
        k_local<<<G, 1024, 0, stream>>>(src, dst, packed, hbT, loff, NBK, G, e);
        k_scanA<<<NBK, 256, 0, stream>>>(hbT, btot, G);
        k_scanB<<<1, 512, 0, stream>>>(btot, bstart, NBK, e);
        k_merge<<<NBK, 512, 0, stream>>>(hbT, loff, btot, bstart, packed, csr,
                                         dinv, rowoff, NBK, G, n);
        csr_p = csr;
    } else {
        const int NB2 = (n + 127) >> 7;                  // 782
        const int G2 = (e + CHUNK2 - 1) / CHUNK2;        // 400
        k_hist_o<<<G2, 512, 0, stream>>>(dst, hbT, NB2, G2, e);
        k_scanA<<<NB2, 256, 0, stream>>>(hbT, btot, G2);
        k_scanB<<<1, 512, 0, stream>>>(btot, bstart, NB2, e);
        k_part_o<<<G2, 512, 0, stream>>>(src, dst, hbT, bstart, packed, NB2, G2, e);
        k_build_o<<<NB2, 256, 0, stream>>>(bstart, packed, dinv, rowoff, n);
        csr_p = packed;
    }

    // Layer 1 GEMV: hsA = (x @ W1) * dinv
    const int wb = (n + 3) / 4;
    k_mm1<<<wb, 256, 0, stream>>>(x, W1, dinv, hsA, n);

    // Layers 1..3: owner-computes gather + fused finalize
    k_gath_fin4<4><<<wb, 256, 0, stream>>>(rowoff, csr_p, hsA, dinv, b1, W2, hsB, n);
    k_gath_fin4<2><<<wb, 256, 0, stream>>>(rowoff, csr_p, hsB, dinv, b2, W3, hsA, n);
    k_gath_fin3<<<wb, 256, 0, stream>>>(rowoff, csr_p, hsA, dinv, b3, Wc, bc, out, hout, n);

    (void)n_in; (void)out_size;
}

// Round 15
// 218.032 us; speedup vs baseline: 1.3367x; 1.0508x over previous
//
#include <hip/hip_runtime.h>
#include <math.h>

// GCN forward: 3x GCNConv (128->4->4->2) + classifier (2->4).
// Build pipeline: ZERO scattered global writes, ZERO global atomics:
//   k_local (1024 thr): per-16384-edge chunk LDS counting sort by 256-node
//            bucket -> coalesced sorted-chunk writeback + hbT + loff
//   scanA/scanB: per-bucket cross-chunk scan -> bstart
//   k_merge (512 thr): per-bucket gather of chunk runs (aligned int4 reads),
//            LDS counting sort by node -> permute into 2nd LDS stage ->
//            fully COALESCED csr write + rowoff + dinv  (r14: the scattered
//            csr store was the last scattered-write in the pipeline)
// Aggregation: owner-computes gather, wave per node, register reduce.

#define LCHUNK 16384
#define CHUNK2 16000   // fallback path chunk
#define MAXNB  512     // 256-node buckets; n <= 131071
#define CAP    18432   // max edges per bucket (mean 16368, sigma~128 -> +16s)
#define MAXNB2 1024    // fallback: 128-node buckets
#define CAP2   9600    // fallback bucket cap

__device__ __forceinline__ int swz_chunk(int bid, int G) {
    if ((G & 7) != 0) return bid;
    return (bid & 7) * (G >> 3) + (bid >> 3);
}

// ---------- chunk-local counting sort (16384 edges, 16/thread, 1024 thr) --
__global__ __launch_bounds__(1024) void k_local(
        const int* __restrict__ src, const int* __restrict__ dst,
        int* __restrict__ packed, int* __restrict__ hbT, int* __restrict__ loff,
        int NBK, int G, int e) {
    __shared__ int hist[MAXNB];
    __shared__ int cur[MAXNB];
    __shared__ int part[1024];
    __shared__ int stage[LCHUNK];
    int g = blockIdx.x, tid = threadIdx.x;
    for (int b = tid; b < NBK; b += 1024) hist[b] = 0;
    __syncthreads();
    int i0 = g * LCHUNK;
    int i1 = min(i0 + LCHUNK, e);
    int val[16], bkt[16];
#pragma unroll
    for (int k = 0; k < 16; k++) {
        int i = i0 + tid + (k << 10);
        bool v = i < i1;
        int d = v ? dst[i] : 0;
        int s = v ? src[i] : 0;
        bkt[k] = v ? (d >> 8) : -1;
        val[k] = ((d & 255) << 17) | s;
        if (v) atomicAdd(&hist[d >> 8], 1);
    }
    __syncthreads();
    // block exclusive scan over NBK counts (1 bucket per thread; NBK<=1024)
    int s0 = (tid < NBK) ? hist[tid] : 0;
    part[tid] = s0;
    __syncthreads();
#pragma unroll
    for (int off = 1; off < 1024; off <<= 1) {
        int u = (tid >= off) ? part[tid - off] : 0;
        __syncthreads();
        part[tid] += u;
        __syncthreads();
    }
    int excl = part[tid] - s0;
    if (tid < NBK) {
        cur[tid] = excl;
        hbT[(size_t)tid * G + g] = s0;
        loff[(size_t)g * NBK + tid] = excl;
    }
    __syncthreads();
#pragma unroll
    for (int k = 0; k < 16; k++) {
        if (bkt[k] >= 0) {
            int p = atomicAdd(&cur[bkt[k]], 1);
            stage[p] = val[k];
        }
    }
    __syncthreads();
    int len = i1 - i0;
    for (int i = tid; i < len; i += 1024)
        packed[i0 + i] = stage[i];
}

// Per-bucket exclusive scan over chunks (block per bucket, contiguous row).
__global__ void k_scanA(int* __restrict__ hbT, int* __restrict__ btot, int G) {
    __shared__ int part[256];
    int b = blockIdx.x, t = threadIdx.x;
    int* row = hbT + (size_t)b * G;
    int C = (G + 255) / 256;
    int lo = t * C, hi = min(lo + C, G);
    int s = 0;
    for (int i = lo; i < hi; i++) s += row[i];
    part[t] = s;
    __syncthreads();
#pragma unroll
    for (int off = 1; off < 256; off <<= 1) {
        int u = (t >= off) ? part[t - off] : 0;
        __syncthreads();
        part[t] += u;
        __syncthreads();
    }
    int run = part[t] - s;
    for (int i = lo; i < hi; i++) {
        int v = row[i];
        row[i] = run;
        run += v;
    }
    if (t == 255) btot[b] = part[255];
}

__global__ void k_scanB(const int* __restrict__ btot, int* __restrict__ bstart,
                        int NB, int e) {
    __shared__ int part[512];
    int t = threadIdx.x;
    int C = (NB + 511) / 512;
    int lo = t * C, hi = min(lo + C, NB);
    int s = 0;
    for (int i = lo; i < hi; i++) s += btot[i];
    part[t] = s;
    __syncthreads();
#pragma unroll
    for (int off = 1; off < 512; off <<= 1) {
        int u = (t >= off) ? part[t - off] : 0;
        __syncthreads();
        part[t] += u;
        __syncthreads();
    }
    int run = part[t] - s;
    for (int i = lo; i < hi; i++) {
        bstart[i] = run;
        run += btot[i];
    }
    if (t == 511) bstart[NB] = e;
}

// Merge runs of one 256-node bucket (aligned int4 reads), counting-sort by
// node into a second LDS stage, fully coalesced csr write. ~150KB LDS,
// 1 block/CU (merge shown occupancy-insensitive, r13).
__global__ __launch_bounds__(512) void k_merge(
        const int* __restrict__ hbT, const int* __restrict__ loff,
        const int* __restrict__ btot, const int* __restrict__ bstart,
        const int* __restrict__ packed, int* __restrict__ csr,
        float* __restrict__ dinv, int* __restrict__ rowoff,
        int NBK, int G, int n) {
    __shared__ int stage[CAP];
    __shared__ int stage2[CAP];
    __shared__ int cnt[256];
    __shared__ int off[256];
    __shared__ int cur[256];
    int b = blockIdx.x, tid = threadIdx.x;
    int btt = btot[b];
    int total = min(btt, CAP);
    for (int g = tid; g < G; g += 512) {
        int o  = hbT[(size_t)b * G + g];
        int nx = (g + 1 < G) ? hbT[(size_t)b * G + g + 1] : btt;
        if (nx > CAP) nx = CAP;
        if (o >= nx) continue;
        int len = nx - o;
        int sp = g * LCHUNK + loff[(size_t)g * NBK + b];
        int a   = sp & ~3;
        int rel = sp - a;                  // 0..3
        int n4  = (rel + len + 3) >> 2;
        for (int q = 0; q < n4; q++) {
            int4 w = *reinterpret_cast<const int4*>(packed + a + q * 4);
            int base = q * 4 - rel;        // index of w.x within run
            if (base >= 0 && base < len)     stage[o + base]     = w.x;
            if (base + 1 >= 0 && base + 1 < len) stage[o + base + 1] = w.y;
            if (base + 2 >= 0 && base + 2 < len) stage[o + base + 2] = w.z;
            if (base + 3 >= 0 && base + 3 < len) stage[o + base + 3] = w.w;
        }
    }
    if (tid < 256) cnt[tid] = 0;
    __syncthreads();
    for (int i = tid; i < total; i += 512) atomicAdd(&cnt[stage[i] >> 17], 1);
    __syncthreads();
    if (tid < 256) off[tid] = cnt[tid];
    __syncthreads();
#pragma unroll
    for (int s = 1; s < 256; s <<= 1) {
        int v = 0;
        if (tid < 256 && tid >= s) v = off[tid - s];
        __syncthreads();
        if (tid < 256 && tid >= s) off[tid] += v;
        __syncthreads();
    }
    if (tid < 256) {
        int excl = off[tid] - cnt[tid];
        int node = (b << 8) + tid;
        if (node < n) dinv[node] = 1.0f / sqrtf((float)(cnt[tid] + 1));
        if (node <= n) rowoff[node] = bstart[b] + excl;
        cur[tid] = excl;
    }
    __syncthreads();
    // permute into stage2 (LDS scatter), then coalesced global write
    for (int i = tid; i < total; i += 512) {
        int w = stage[i];
        int p = atomicAdd(&cur[w >> 17], 1);
        stage2[p] = w & 0x1FFFF;
    }
    __syncthreads();
    int base = bstart[b];
    for (int i = tid; i < total; i += 512)
        csr[base + i] = stage2[i];
}

// ---------- fallback path (r9): global-scatter partition, 128-buckets ----
__global__ void k_hist_o(const int* __restrict__ dst, int* __restrict__ hbT,
                         int NB, int G, int e) {
    __shared__ int hist[MAXNB2];
    int g = swz_chunk(blockIdx.x, G);
    for (int b = threadIdx.x; b < NB; b += 512) hist[b] = 0;
    __syncthreads();
    long long i0 = (long long)g * CHUNK2;
    int i1 = (int)min(i0 + CHUNK2, (long long)e);
    for (int i = (int)i0 + threadIdx.x; i < i1; i += 512)
        atomicAdd(&hist[dst[i] >> 7], 1);
    __syncthreads();
    for (int b = threadIdx.x; b < NB; b += 512)
        hbT[(size_t)b * G + g] = hist[b];
}

__global__ void k_part_o(const int* __restrict__ src, const int* __restrict__ dst,
                         const int* __restrict__ hbT, const int* __restrict__ bstart,
                         int* __restrict__ packed, int NB, int G, int e) {
    __shared__ int cur[MAXNB2];
    int g = swz_chunk(blockIdx.x, G);
    for (int b = threadIdx.x; b < NB; b += 512)
        cur[b] = hbT[(size_t)b * G + g] + bstart[b];
    __syncthreads();
    long long i0 = (long long)g * CHUNK2;
    int i1 = (int)min(i0 + CHUNK2, (long long)e);
    for (int i = (int)i0 + threadIdx.x; i < i1; i += 512) {
        int d = dst[i], s = src[i];
        int pos = atomicAdd(&cur[d >> 7], 1);
        packed[pos] = ((d & 127) << 17) | s;
    }
}

__global__ void k_build_o(const int* __restrict__ bstart, int* __restrict__ packed,
                          float* __restrict__ dinv, int* __restrict__ rowoff, int n) {
    __shared__ int stage[CAP2];
    __shared__ int cnt[128];
    __shared__ int off[128];
    __shared__ int cur[128];
    int b = blockIdx.x, tid = threadIdx.x;
    int lo = bstart[b];
    int len = bstart[b + 1] - lo;
    if (len > CAP2) len = CAP2;
    if (tid < 128) cnt[tid] = 0;
    for (int i = tid; i < len; i += 256) stage[i] = packed[lo + i];
    __syncthreads();
    for (int i = tid; i < len; i += 256) atomicAdd(&cnt[stage[i] >> 17], 1);
    __syncthreads();
    if (tid < 128) off[tid] = cnt[tid];
    __syncthreads();
#pragma unroll
    for (int s = 1; s < 128; s <<= 1) {
        int v = 0;
        if (tid < 128 && tid >= s) v = off[tid - s];
        __syncthreads();
        if (tid < 128 && tid >= s) off[tid] += v;
        __syncthreads();
    }
    if (tid < 128) {
        int excl = off[tid] - cnt[tid];
        int node = (b << 7) + tid;
        if (node < n) dinv[node] = 1.0f / sqrtf((float)(cnt[tid] + 1));
        if (node <= n) rowoff[node] = lo + excl;
        cur[tid] = excl;
    }
    __syncthreads();
    for (int i = tid; i < len; i += 256) {
        int w = stage[i];
        int p = atomicAdd(&cur[w >> 17], 1);
        packed[lo + p] = w & 0x1FFFF;
    }
}

// ---------- compute kernels ----------
__global__ void k_mm1(const float* __restrict__ x, const float* __restrict__ W,
                      const float* __restrict__ dinv, float* __restrict__ hs, int n) {
    int gid = blockIdx.x * blockDim.x + threadIdx.x;
    int node = gid >> 6;
    int lane = threadIdx.x & 63;
    if (node >= n) return;
    const float2 xv = *reinterpret_cast<const float2*>(x + (size_t)node * 128 + lane * 2);
    const float4 w0 = *reinterpret_cast<const float4*>(W + (lane * 2) * 4);
    const float4 w1 = *reinterpret_cast<const float4*>(W + (lane * 2 + 1) * 4);
    float a0 = xv.x * w0.x + xv.y * w1.x;
    float a1 = xv.x * w0.y + xv.y * w1.y;
    float a2 = xv.x * w0.z + xv.y * w1.z;
    float a3 = xv.x * w0.w + xv.y * w1.w;
#pragma unroll
    for (int m = 32; m >= 1; m >>= 1) {
        a0 += __shfl_xor(a0, m);
        a1 += __shfl_xor(a1, m);
        a2 += __shfl_xor(a2, m);
        a3 += __shfl_xor(a3, m);
    }
    if (lane == 0) {
        float di = dinv[node];
        *reinterpret_cast<float4*>(hs + (size_t)node * 4) =
            make_float4(a0 * di, a1 * di, a2 * di, a3 * di);
    }
}

template <int FOUT>
__global__ void k_gath_fin4(const int* __restrict__ rowoff, const int* __restrict__ csr,
                            const float* __restrict__ hs, const float* __restrict__ dinv,
                            const float* __restrict__ b, const float* __restrict__ Wn,
                            float* __restrict__ hsn, int n) {
    int gid = blockIdx.x * blockDim.x + threadIdx.x;
    int node = gid >> 6;
    int lane = threadIdx.x & 63;
    if (node >= n) return;
    int start = rowoff[node], end = rowoff[node + 1];
    float a0 = 0.f, a1 = 0.f, a2 = 0.f, a3 = 0.f;
    for (int j = start + lane; j < end; j += 64) {
        int s = csr[j];
        float4 v = *reinterpret_cast<const float4*>(hs + (size_t)s * 4);
        a0 += v.x; a1 += v.y; a2 += v.z; a3 += v.w;
    }
#pragma unroll
    for (int m = 32; m >= 1; m >>= 1) {
        a0 += __shfl_xor(a0, m);
        a1 += __shfl_xor(a1, m);
        a2 += __shfl_xor(a2, m);
        a3 += __shfl_xor(a3, m);
    }
    if (lane == 0) {
        float4 s = *reinterpret_cast<const float4*>(hs + (size_t)node * 4);
        float di = dinv[node];
        float h0 = tanhf((a0 + s.x) * di + b[0]);
        float h1 = tanhf((a1 + s.y) * di + b[1]);
        float h2 = tanhf((a2 + s.z) * di + b[2]);
        float h3 = tanhf((a3 + s.w) * di + b[3]);
        float o[FOUT];
#pragma unroll
        for (int j = 0; j < FOUT; j++) {
            o[j] = (h0 * Wn[0 * FOUT + j] + h1 * Wn[1 * FOUT + j] +
                    h2 * Wn[2 * FOUT + j] + h3 * Wn[3 * FOUT + j]) * di;
        }
        if constexpr (FOUT == 4) {
            *reinterpret_cast<float4*>(hsn + (size_t)node * 4) =
                make_float4(o[0], o[1], o[2], o[3]);
        } else {
            *reinterpret_cast<float2*>(hsn + (size_t)node * 2) = make_float2(o[0], o[1]);
        }
    }
}

__global__ void k_gath_fin3(const int* __restrict__ rowoff, const int* __restrict__ csr,
                            const float* __restrict__ hs, const float* __restrict__ dinv,
                            const float* __restrict__ b3, const float* __restrict__ Wc,
                            const float* __restrict__ bc, float* __restrict__ out,
                            float* __restrict__ hout, int n) {
    int gid = blockIdx.x * blockDim.x + threadIdx.x;
    int node = gid >> 6;
    int lane = threadIdx.x & 63;
    if (node >= n) return;
    int start = rowoff[node], end = rowoff[node + 1];
    float a0 = 0.f, a1 = 0.f;
    for (int j = start + lane; j < end; j += 64) {
        int s = csr[j];
        float2 v = *reinterpret_cast<const float2*>(hs + (size_t)s * 2);
        a0 += v.x; a1 += v.y;
    }
#pragma unroll
    for (int m = 32; m >= 1; m >>= 1) {
        a0 += __shfl_xor(a0, m);
        a1 += __shfl_xor(a1, m);
    }
    if (lane == 0) {
        float2 s = *reinterpret_cast<const float2*>(hs + (size_t)node * 2);
        float di = dinv[node];
        float h0 = tanhf((a0 + s.x) * di + b3[0]);
        float h1 = tanhf((a1 + s.y) * di + b3[1]);
        *reinterpret_cast<float2*>(hout + (size_t)node * 2) = make_float2(h0, h1);
        float4 o;
        o.x = h0 * Wc[0] + h1 * Wc[4] + bc[0];
        o.y = h0 * Wc[1] + h1 * Wc[5] + bc[1];
        o.z = h0 * Wc[2] + h1 * Wc[6] + bc[2];
        o.w = h0 * Wc[3] + h1 * Wc[7] + bc[3];
        *reinterpret_cast<float4*>(out + (size_t)node * 4) = o;
    }
}

extern "C" void kernel_launch(void* const* d_in, const int* in_sizes, int n_in,
                              void* d_out, int out_size, void* d_ws, size_t ws_size,
                              hipStream_t stream) {
    const float* x  = (const float*)d_in[0];
    const int*  ei  = (const int*)d_in[1];
    const float* W1 = (const float*)d_in[2];
    const float* b1 = (const float*)d_in[3];
    const float* W2 = (const float*)d_in[4];
    const float* b2 = (const float*)d_in[5];
    const float* W3 = (const float*)d_in[6];
    const float* b3 = (const float*)d_in[7];
    const float* Wc = (const float*)d_in[8];
    const float* bc = (const float*)d_in[9];

    const int n = in_sizes[0] / 128;
    const int e = in_sizes[1] / 2;
    const int* src = ei;
    const int* dst = ei + e;

    const size_t MB = 1024 * 1024;
    char* ws = (char*)d_ws;
    float* dinv   = (float*)(ws + 0);                    // n floats
    float* hsA    = (float*)(ws + MB / 2);               // n*4 floats
    float* hsB    = (float*)(ws + 2 * MB + MB / 2);      // n*4 floats
    int*   rowoff = (int*)  (ws + 4 * MB + MB / 2);      // n+1 ints
    int*   btot   = (int*)  (ws + 5 * MB);               // NBK ints
    int*   bstart = (int*)  (ws + 5 * MB + 16 * 1024);   // NBK+1 ints
    int*   hbT    = (int*)  (ws + 5 * MB + MB / 2);      // NBK*G ints
    int*   loff   = (int*)  (ws + 8 * MB);               // G*NBK ints (new path)
    int*   packed = (int*)  (ws + 10 * MB + MB / 2);     // e ints (25.6 MB)
    int*   csr    = (int*)  (ws + 36 * MB + MB / 2);     // e ints (new path)

    float* out  = (float*)d_out;
    float* hout = out + (size_t)n * 4;

    const size_t need_new = 36 * MB + MB / 2 + (size_t)e * 4 + MB;
    const bool use_new = ws_size >= need_new;

    const int* csr_p;
    if (use_new) {
        const int NBK = (n + 255) >> 8;                  // 391
        const int G = (e + LCHUNK - 1) / LCHUNK;         // 391
        k_local<<<G, 1024, 0, stream>>>(src, dst, packed, hbT, loff, NBK, G, e);
        k_scanA<<<NBK, 256, 0, stream>>>(hbT, btot, G);
        k_scanB<<<1, 512, 0, stream>>>(btot, bstart, NBK, e);
        k_merge<<<NBK, 512, 0, stream>>>(hbT, loff, btot, bstart, packed, csr,
                                         dinv, rowoff, NBK, G, n);
        csr_p = csr;
    } else {
        const int NB2 = (n + 127) >> 7;                  // 782
        const int G2 = (e + CHUNK2 - 1) / CHUNK2;        // 400
        k_hist_o<<<G2, 512, 0, stream>>>(dst, hbT, NB2, G2, e);
        k_scanA<<<NB2, 256, 0, stream>>>(hbT, btot, G2);
        k_scanB<<<1, 512, 0, stream>>>(btot, bstart, NB2, e);
        k_part_o<<<G2, 512, 0, stream>>>(src, dst, hbT, bstart, packed, NB2, G2, e);
        k_build_o<<<NB2, 256, 0, stream>>>(bstart, packed, dinv, rowoff, n);
        csr_p = packed;
    }

    // Layer 1 GEMV: hsA = (x @ W1) * dinv
    const int wb = (n + 3) / 4;
    k_mm1<<<wb, 256, 0, stream>>>(x, W1, dinv, hsA, n);

    // Layers 1..3: owner-computes gather + fused finalize
    k_gath_fin4<4><<<wb, 256, 0, stream>>>(rowoff, csr_p, hsA, dinv, b1, W2, hsB, n);
    k_gath_fin4<2><<<wb, 256, 0, stream>>>(rowoff, csr_p, hsB, dinv, b2, W3, hsA, n);
    k_gath_fin3<<<wb, 256, 0, stream>>>(rowoff, csr_p, hsA, dinv, b3, Wc, bc, out, hout, n);

    (void)n_in; (void)out_size;
}

// Round 16
// 201.339 us; speedup vs baseline: 1.4475x; 1.0829x over previous
//
#include <hip/hip_runtime.h>
#include <math.h>

// GCN forward: 3x GCNConv (128->4->4->2) + classifier (2->4).
// Build: ZERO scattered global writes / atomics (k_local chunk sort ->
// scans -> k_merge 2-stage LDS sort, coalesced csr).
// Aggregation (r15): quarter-wave (16-lane) gather per node (4 nodes/wave
// share shuffles) writing raw agg; separate node-parallel k_fin does
// tanh + next-layer matmul with full lane utilization (was lane0-serial).

#define LCHUNK 16384
#define CHUNK2 16000   // fallback path chunk
#define MAXNB  512     // 256-node buckets; n <= 131071
#define CAP    18432   // max edges per bucket (mean 16368, sigma~128 -> +16s)
#define MAXNB2 1024    // fallback: 128-node buckets
#define CAP2   9600    // fallback bucket cap

__device__ __forceinline__ int swz_chunk(int bid, int G) {
    if ((G & 7) != 0) return bid;
    return (bid & 7) * (G >> 3) + (bid >> 3);
}

// ---------- chunk-local counting sort (16384 edges, 16/thread, 1024 thr) --
__global__ __launch_bounds__(1024) void k_local(
        const int* __restrict__ src, const int* __restrict__ dst,
        int* __restrict__ packed, int* __restrict__ hbT, int* __restrict__ loff,
        int NBK, int G, int e) {
    __shared__ int hist[MAXNB];
    __shared__ int cur[MAXNB];
    __shared__ int part[1024];
    __shared__ int stage[LCHUNK];
    int g = blockIdx.x, tid = threadIdx.x;
    for (int b = tid; b < NBK; b += 1024) hist[b] = 0;
    __syncthreads();
    int i0 = g * LCHUNK;
    int i1 = min(i0 + LCHUNK, e);
    int val[16], bkt[16];
#pragma unroll
    for (int k = 0; k < 16; k++) {
        int i = i0 + tid + (k << 10);
        bool v = i < i1;
        int d = v ? dst[i] : 0;
        int s = v ? src[i] : 0;
        bkt[k] = v ? (d >> 8) : -1;
        val[k] = ((d & 255) << 17) | s;
        if (v) atomicAdd(&hist[d >> 8], 1);
    }
    __syncthreads();
    int s0 = (tid < NBK) ? hist[tid] : 0;
    part[tid] = s0;
    __syncthreads();
#pragma unroll
    for (int off = 1; off < 1024; off <<= 1) {
        int u = (tid >= off) ? part[tid - off] : 0;
        __syncthreads();
        part[tid] += u;
        __syncthreads();
    }
    int excl = part[tid] - s0;
    if (tid < NBK) {
        cur[tid] = excl;
        hbT[(size_t)tid * G + g] = s0;
        loff[(size_t)g * NBK + tid] = excl;
    }
    __syncthreads();
#pragma unroll
    for (int k = 0; k < 16; k++) {
        if (bkt[k] >= 0) {
            int p = atomicAdd(&cur[bkt[k]], 1);
            stage[p] = val[k];
        }
    }
    __syncthreads();
    int len = i1 - i0;
    for (int i = tid; i < len; i += 1024)
        packed[i0 + i] = stage[i];
}

// Per-bucket exclusive scan over chunks (block per bucket, contiguous row).
__global__ void k_scanA(int* __restrict__ hbT, int* __restrict__ btot, int G) {
    __shared__ int part[256];
    int b = blockIdx.x, t = threadIdx.x;
    int* row = hbT + (size_t)b * G;
    int C = (G + 255) / 256;
    int lo = t * C, hi = min(lo + C, G);
    int s = 0;
    for (int i = lo; i < hi; i++) s += row[i];
    part[t] = s;
    __syncthreads();
#pragma unroll
    for (int off = 1; off < 256; off <<= 1) {
        int u = (t >= off) ? part[t - off] : 0;
        __syncthreads();
        part[t] += u;
        __syncthreads();
    }
    int run = part[t] - s;
    for (int i = lo; i < hi; i++) {
        int v = row[i];
        row[i] = run;
        run += v;
    }
    if (t == 255) btot[b] = part[255];
}

__global__ void k_scanB(const int* __restrict__ btot, int* __restrict__ bstart,
                        int NB, int e) {
    __shared__ int part[512];
    int t = threadIdx.x;
    int C = (NB + 511) / 512;
    int lo = t * C, hi = min(lo + C, NB);
    int s = 0;
    for (int i = lo; i < hi; i++) s += btot[i];
    part[t] = s;
    __syncthreads();
#pragma unroll
    for (int off = 1; off < 512; off <<= 1) {
        int u = (t >= off) ? part[t - off] : 0;
        __syncthreads();
        part[t] += u;
        __syncthreads();
    }
    int run = part[t] - s;
    for (int i = lo; i < hi; i++) {
        bstart[i] = run;
        run += btot[i];
    }
    if (t == 511) bstart[NB] = e;
}

// Merge runs of one 256-node bucket, 2-stage LDS sort, coalesced csr write.
__global__ __launch_bounds__(512) void k_merge(
        const int* __restrict__ hbT, const int* __restrict__ loff,
        const int* __restrict__ btot, const int* __restrict__ bstart,
        const int* __restrict__ packed, int* __restrict__ csr,
        float* __restrict__ dinv, int* __restrict__ rowoff,
        int NBK, int G, int n) {
    __shared__ int stage[CAP];
    __shared__ int stage2[CAP];
    __shared__ int cnt[256];
    __shared__ int off[256];
    __shared__ int cur[256];
    int b = blockIdx.x, tid = threadIdx.x;
    int btt = btot[b];
    int total = min(btt, CAP);
    for (int g = tid; g < G; g += 512) {
        int o  = hbT[(size_t)b * G + g];
        int nx = (g + 1 < G) ? hbT[(size_t)b * G + g + 1] : btt;
        if (nx > CAP) nx = CAP;
        if (o >= nx) continue;
        int len = nx - o;
        int sp = g * LCHUNK + loff[(size_t)g * NBK + b];
        int a   = sp & ~3;
        int rel = sp - a;
        int n4  = (rel + len + 3) >> 2;
        for (int q = 0; q < n4; q++) {
            int4 w = *reinterpret_cast<const int4*>(packed + a + q * 4);
            int base = q * 4 - rel;
            if (base >= 0 && base < len)     stage[o + base]     = w.x;
            if (base + 1 >= 0 && base + 1 < len) stage[o + base + 1] = w.y;
            if (base + 2 >= 0 && base + 2 < len) stage[o + base + 2] = w.z;
            if (base + 3 >= 0 && base + 3 < len) stage[o + base + 3] = w.w;
        }
    }
    if (tid < 256) cnt[tid] = 0;
    __syncthreads();
    for (int i = tid; i < total; i += 512) atomicAdd(&cnt[stage[i] >> 17], 1);
    __syncthreads();
    if (tid < 256) off[tid] = cnt[tid];
    __syncthreads();
#pragma unroll
    for (int s = 1; s < 256; s <<= 1) {
        int v = 0;
        if (tid < 256 && tid >= s) v = off[tid - s];
        __syncthreads();
        if (tid < 256 && tid >= s) off[tid] += v;
        __syncthreads();
    }
    if (tid < 256) {
        int excl = off[tid] - cnt[tid];
        int node = (b << 8) + tid;
        if (node < n) dinv[node] = 1.0f / sqrtf((float)(cnt[tid] + 1));
        if (node <= n) rowoff[node] = bstart[b] + excl;
        cur[tid] = excl;
    }
    __syncthreads();
    for (int i = tid; i < total; i += 512) {
        int w = stage[i];
        int p = atomicAdd(&cur[w >> 17], 1);
        stage2[p] = w & 0x1FFFF;
    }
    __syncthreads();
    int base = bstart[b];
    for (int i = tid; i < total; i += 512)
        csr[base + i] = stage2[i];
}

// ---------- fallback path (r9): global-scatter partition, 128-buckets ----
__global__ void k_hist_o(const int* __restrict__ dst, int* __restrict__ hbT,
                         int NB, int G, int e) {
    __shared__ int hist[MAXNB2];
    int g = swz_chunk(blockIdx.x, G);
    for (int b = threadIdx.x; b < NB; b += 512) hist[b] = 0;
    __syncthreads();
    long long i0 = (long long)g * CHUNK2;
    int i1 = (int)min(i0 + CHUNK2, (long long)e);
    for (int i = (int)i0 + threadIdx.x; i < i1; i += 512)
        atomicAdd(&hist[dst[i] >> 7], 1);
    __syncthreads();
    for (int b = threadIdx.x; b < NB; b += 512)
        hbT[(size_t)b * G + g] = hist[b];
}

__global__ void k_part_o(const int* __restrict__ src, const int* __restrict__ dst,
                         const int* __restrict__ hbT, const int* __restrict__ bstart,
                         int* __restrict__ packed, int NB, int G, int e) {
    __shared__ int cur[MAXNB2];
    int g = swz_chunk(blockIdx.x, G);
    for (int b = threadIdx.x; b < NB; b += 512)
        cur[b] = hbT[(size_t)b * G + g] + bstart[b];
    __syncthreads();
    long long i0 = (long long)g * CHUNK2;
    int i1 = (int)min(i0 + CHUNK2, (long long)e);
    for (int i = (int)i0 + threadIdx.x; i < i1; i += 512) {
        int d = dst[i], s = src[i];
        int pos = atomicAdd(&cur[d >> 7], 1);
        packed[pos] = ((d & 127) << 17) | s;
    }
}

__global__ void k_build_o(const int* __restrict__ bstart, int* __restrict__ packed,
                          float* __restrict__ dinv, int* __restrict__ rowoff, int n) {
    __shared__ int stage[CAP2];
    __shared__ int cnt[128];
    __shared__ int off[128];
    __shared__ int cur[128];
    int b = blockIdx.x, tid = threadIdx.x;
    int lo = bstart[b];
    int len = bstart[b + 1] - lo;
    if (len > CAP2) len = CAP2;
    if (tid < 128) cnt[tid] = 0;
    for (int i = tid; i < len; i += 256) stage[i] = packed[lo + i];
    __syncthreads();
    for (int i = tid; i < len; i += 256) atomicAdd(&cnt[stage[i] >> 17], 1);
    __syncthreads();
    if (tid < 128) off[tid] = cnt[tid];
    __syncthreads();
#pragma unroll
    for (int s = 1; s < 128; s <<= 1) {
        int v = 0;
        if (tid < 128 && tid >= s) v = off[tid - s];
        __syncthreads();
        if (tid < 128 && tid >= s) off[tid] += v;
        __syncthreads();
    }
    if (tid < 128) {
        int excl = off[tid] - cnt[tid];
        int node = (b << 7) + tid;
        if (node < n) dinv[node] = 1.0f / sqrtf((float)(cnt[tid] + 1));
        if (node <= n) rowoff[node] = lo + excl;
        cur[tid] = excl;
    }
    __syncthreads();
    for (int i = tid; i < len; i += 256) {
        int w = stage[i];
        int p = atomicAdd(&cur[w >> 17], 1);
        packed[lo + p] = w & 0x1FFFF;
    }
}

// ---------- compute kernels ----------
__global__ void k_mm1(const float* __restrict__ x, const float* __restrict__ W,
                      const float* __restrict__ dinv, float* __restrict__ hs, int n) {
    int gid = blockIdx.x * blockDim.x + threadIdx.x;
    int node = gid >> 6;
    int lane = threadIdx.x & 63;
    if (node >= n) return;
    const float2 xv = *reinterpret_cast<const float2*>(x + (size_t)node * 128 + lane * 2);
    const float4 w0 = *reinterpret_cast<const float4*>(W + (lane * 2) * 4);
    const float4 w1 = *reinterpret_cast<const float4*>(W + (lane * 2 + 1) * 4);
    float a0 = xv.x * w0.x + xv.y * w1.x;
    float a1 = xv.x * w0.y + xv.y * w1.y;
    float a2 = xv.x * w0.z + xv.y * w1.z;
    float a3 = xv.x * w0.w + xv.y * w1.w;
#pragma unroll
    for (int m = 32; m >= 1; m >>= 1) {
        a0 += __shfl_xor(a0, m);
        a1 += __shfl_xor(a1, m);
        a2 += __shfl_xor(a2, m);
        a3 += __shfl_xor(a3, m);
    }
    if (lane == 0) {
        float di = dinv[node];
        *reinterpret_cast<float4*>(hs + (size_t)node * 4) =
            make_float4(a0 * di, a1 * di, a2 * di, a3 * di);
    }
}

// Quarter-wave gather (16 lanes/node, 4 nodes share each shuffle).
__global__ void k_gath4(const int* __restrict__ rowoff, const int* __restrict__ csr,
                        const float* __restrict__ hs, float* __restrict__ agg, int n) {
    int gid = blockIdx.x * blockDim.x + threadIdx.x;
    int node = gid >> 4;
    int sub = threadIdx.x & 15;
    if (node >= n) return;
    int start = rowoff[node], end = rowoff[node + 1];
    float a0 = 0.f, a1 = 0.f, a2 = 0.f, a3 = 0.f;
    for (int j = start + sub; j < end; j += 16) {
        int s = csr[j];
        float4 v = *reinterpret_cast<const float4*>(hs + (size_t)s * 4);
        a0 += v.x; a1 += v.y; a2 += v.z; a3 += v.w;
    }
#pragma unroll
    for (int m = 8; m >= 1; m >>= 1) {
        a0 += __shfl_xor(a0, m);
        a1 += __shfl_xor(a1, m);
        a2 += __shfl_xor(a2, m);
        a3 += __shfl_xor(a3, m);
    }
    if (sub == 0)
        *reinterpret_cast<float4*>(agg + (size_t)node * 4) =
            make_float4(a0, a1, a2, a3);
}

__global__ void k_gath2(const int* __restrict__ rowoff, const int* __restrict__ csr,
                        const float* __restrict__ hs, float* __restrict__ agg, int n) {
    int gid = blockIdx.x * blockDim.x + threadIdx.x;
    int node = gid >> 4;
    int sub = threadIdx.x & 15;
    if (node >= n) return;
    int start = rowoff[node], end = rowoff[node + 1];
    float a0 = 0.f, a1 = 0.f;
    for (int j = start + sub; j < end; j += 16) {
        int s = csr[j];
        float2 v = *reinterpret_cast<const float2*>(hs + (size_t)s * 2);
        a0 += v.x; a1 += v.y;
    }
#pragma unroll
    for (int m = 8; m >= 1; m >>= 1) {
        a0 += __shfl_xor(a0, m);
        a1 += __shfl_xor(a1, m);
    }
    if (sub == 0)
        *reinterpret_cast<float2*>(agg + (size_t)node * 2) = make_float2(a0, a1);
}

// Node-parallel finalize: h = tanh((agg+hs)*dinv + b); hsn = (h@Wn)*dinv.
template <int FOUT>
__global__ void k_fin4(const float* __restrict__ agg, const float* __restrict__ hs,
                       const float* __restrict__ dinv, const float* __restrict__ b_,
                       const float* __restrict__ Wn, float* __restrict__ hsn, int n) {
    int i = blockIdx.x * blockDim.x + threadIdx.x;
    if (i >= n) return;
    float4 a = *reinterpret_cast<const float4*>(agg + (size_t)i * 4);
    float4 s = *reinterpret_cast<const float4*>(hs + (size_t)i * 4);
    float di = dinv[i];
    float h0 = tanhf((a.x + s.x) * di + b_[0]);
    float h1 = tanhf((a.y + s.y) * di + b_[1]);
    float h2 = tanhf((a.z + s.z) * di + b_[2]);
    float h3 = tanhf((a.w + s.w) * di + b_[3]);
    float o[FOUT];
#pragma unroll
    for (int j = 0; j < FOUT; j++) {
        o[j] = (h0 * Wn[0 * FOUT + j] + h1 * Wn[1 * FOUT + j] +
                h2 * Wn[2 * FOUT + j] + h3 * Wn[3 * FOUT + j]) * di;
    }
    if constexpr (FOUT == 4) {
        *reinterpret_cast<float4*>(hsn + (size_t)i * 4) =
            make_float4(o[0], o[1], o[2], o[3]);
    } else {
        *reinterpret_cast<float2*>(hsn + (size_t)i * 2) = make_float2(o[0], o[1]);
    }
}

__global__ void k_fin3(const float* __restrict__ agg, const float* __restrict__ hs,
                       const float* __restrict__ dinv, const float* __restrict__ b3,
                       const float* __restrict__ Wc, const float* __restrict__ bc,
                       float* __restrict__ out, float* __restrict__ hout, int n) {
    int i = blockIdx.x * blockDim.x + threadIdx.x;
    if (i >= n) return;
    float2 a = *reinterpret_cast<const float2*>(agg + (size_t)i * 2);
    float2 s = *reinterpret_cast<const float2*>(hs + (size_t)i * 2);
    float di = dinv[i];
    float h0 = tanhf((a.x + s.x) * di + b3[0]);
    float h1 = tanhf((a.y + s.y) * di + b3[1]);
    *reinterpret_cast<float2*>(hout + (size_t)i * 2) = make_float2(h0, h1);
    float4 o;
    o.x = h0 * Wc[0] + h1 * Wc[4] + bc[0];
    o.y = h0 * Wc[1] + h1 * Wc[5] + bc[1];
    o.z = h0 * Wc[2] + h1 * Wc[6] + bc[2];
    o.w = h0 * Wc[3] + h1 * Wc[7] + bc[3];
    *reinterpret_cast<float4*>(out + (size_t)i * 4) = o;
}

extern "C" void kernel_launch(void* const* d_in, const int* in_sizes, int n_in,
                              void* d_out, int out_size, void* d_ws, size_t ws_size,
                              hipStream_t stream) {
    const float* x  = (const float*)d_in[0];
    const int*  ei  = (const int*)d_in[1];
    const float* W1 = (const float*)d_in[2];
    const float* b1 = (const float*)d_in[3];
    const float* W2 = (const float*)d_in[4];
    const float* b2 = (const float*)d_in[5];
    const float* W3 = (const float*)d_in[6];
    const float* b3 = (const float*)d_in[7];
    const float* Wc = (const float*)d_in[8];
    const float* bc = (const float*)d_in[9];

    const int n = in_sizes[0] / 128;
    const int e = in_sizes[1] / 2;
    const int* src = ei;
    const int* dst = ei + e;

    const size_t MB = 1024 * 1024;
    char* ws = (char*)d_ws;
    float* dinv   = (float*)(ws + 0);                    // n floats
    float* hsA    = (float*)(ws + MB / 2);               // n*4 floats
    float* hsB    = (float*)(ws + 2 * MB + MB / 2);      // n*4 floats
    int*   rowoff = (int*)  (ws + 4 * MB + MB / 2);      // n+1 ints
    int*   btot   = (int*)  (ws + 5 * MB);               // NBK ints
    int*   bstart = (int*)  (ws + 5 * MB + 16 * 1024);   // NBK+1 ints
    int*   hbT    = (int*)  (ws + 5 * MB + MB / 2);      // NBK*G ints
    float* agg    = (float*)(ws + 8 * MB);               // n*4 floats (1.6MB)
    int*   loff   = (int*)  (ws + 10 * MB);              // G*NBK ints
    int*   packed = (int*)  (ws + 12 * MB);              // e ints (25.6 MB)
    int*   csr    = (int*)  (ws + 38 * MB);              // e ints (new path)

    float* out  = (float*)d_out;
    float* hout = out + (size_t)n * 4;

    const size_t need_new = 38 * MB + (size_t)e * 4 + MB;
    const bool use_new = ws_size >= need_new;

    const int* csr_p;
    if (use_new) {
        const int NBK = (n + 255) >> 8;                  // 391
        const int G = (e + LCHUNK - 1) / LCHUNK;         // 391
        k_local<<<G, 1024, 0, stream>>>(src, dst, packed, hbT, loff, NBK, G, e);
        k_scanA<<<NBK, 256, 0, stream>>>(hbT, btot, G);
        k_scanB<<<1, 512, 0, stream>>>(btot, bstart, NBK, e);
        k_merge<<<NBK, 512, 0, stream>>>(hbT, loff, btot, bstart, packed, csr,
                                         dinv, rowoff, NBK, G, n);
        csr_p = csr;
    } else {
        const int NB2 = (n + 127) >> 7;                  // 782
        const int G2 = (e + CHUNK2 - 1) / CHUNK2;        // 400
        k_hist_o<<<G2, 512, 0, stream>>>(dst, hbT, NB2, G2, e);
        k_scanA<<<NB2, 256, 0, stream>>>(hbT, btot, G2);
        k_scanB<<<1, 512, 0, stream>>>(btot, bstart, NB2, e);
        k_part_o<<<G2, 512, 0, stream>>>(src, dst, hbT, bstart, packed, NB2, G2, e);
        k_build_o<<<NB2, 256, 0, stream>>>(bstart, packed, dinv, rowoff, n);
        csr_p = packed;
    }

    // Layer 1 GEMV: hsA = (x @ W1) * dinv
    const int wb = (n + 3) / 4;       // wave-per-node (mm1)
    const int qb = (n + 15) / 16;     // quarter-wave-per-node (gathers)
    const int nb = (n + 255) / 256;   // node-parallel (finalize)
    k_mm1<<<wb, 256, 0, stream>>>(x, W1, dinv, hsA, n);

    // Layers 1..3: quarter-wave gather -> node-parallel finalize
    k_gath4<<<qb, 256, 0, stream>>>(rowoff, csr_p, hsA, agg, n);
    k_fin4<4><<<nb, 256, 0, stream>>>(agg, hsA, dinv, b1, W2, hsB, n);
    k_gath4<<<qb, 256, 0, stream>>>(rowoff, csr_p, hsB, agg, n);
    k_fin4<2><<<nb, 256, 0, stream>>>(agg, hsB, dinv, b2, W3, hsA, n);
    k_gath2<<<qb, 256, 0, stream>>>(rowoff, csr_p, hsA, agg, n);
    k_fin3<<<nb, 256, 0, stream>>>(agg, hsA, dinv, b3, Wc, bc, out, hout, n);

    (void)n_in; (void)out_size;
}